// Round 5
// baseline (202.583 us; speedup 1.0000x reference)
//
#include <hip/hip_runtime.h>
#include <math.h>

typedef unsigned short u16;
typedef unsigned int u32;
typedef __attribute__((ext_vector_type(8))) short bf16x8;
typedef __attribute__((ext_vector_type(4))) float f32x4;

#define SCALE_ 0.21022410381342864f   // 512^{-1/4}
#define EPS_ 1e-6f
#define RSQM_ 0.0625f                 // 1/sqrt(256)
#define L_ 8192

__device__ __forceinline__ u16 bfhi(float x) {
    u32 u = __float_as_uint(x);
    return (u16)((u + 0x7FFFu + ((u >> 16) & 1u)) >> 16);  // RNE bf16
}
__device__ __forceinline__ float bf2f(u16 h) {
    return __uint_as_float(((u32)h) << 16);
}
__device__ __forceinline__ void split2(float x, u16& h, u16& l) {
    h = bfhi(x);
    l = bfhi(x - bf2f(h));
}
__device__ __forceinline__ u32 okey(float x) {   // order-preserving float->u32
    u32 b = __float_as_uint(x);
    return (b & 0x80000000u) ? ~b : (b | 0x80000000u);
}
__device__ __forceinline__ float odec(u32 k) {
    return (k & 0x80000000u) ? __uint_as_float(k & 0x7fffffffu) : __uint_as_float(~k);
}

#define GLDS16(gsrc, ldst) \
    __builtin_amdgcn_global_load_lds((__attribute__((address_space(1))) void*)(gsrc), \
                                     (__attribute__((address_space(3))) void*)(ldst), 16, 0, 0)

__global__ void init_k(u32* __restrict__ bmax) {
    if (threadIdx.x < 4) bmax[threadIdx.x] = 0u;
}

__global__ __launch_bounds__(256) void split_p(const float* __restrict__ P,
        u16* __restrict__ Ph, u16* __restrict__ Pl) {
    int i = blockIdx.x * 256 + threadIdx.x;
    u16 h, l; split2(P[i], h, l);
    Ph[i] = h; Pl[i] = l;
}

// ---------------------------------------------------------------------------
// Fused dash GEMM, Q and K tiles in ONE grid-512 launch. Tile 128x256, 512thr.
// 2-phase double-buffered LDS + XOR bank swizzle (slot ^= (row>>1)&3).
// Even blocks: Q (rowmax+exp -> Qf bf16). Odd: K (exp(dash-diag) -> KfE + bmax).
// ---------------------------------------------------------------------------
__global__ __launch_bounds__(512) void dash_all(
        const float* __restrict__ Qg, const float* __restrict__ Kg,
        const u16* __restrict__ Bh_g, const u16* __restrict__ Bl_g,
        u16* __restrict__ QF, u16* __restrict__ KfE, u32* __restrict__ bmax) {
    __shared__ __align__(16) u16 Ah[2][128 * 32], Al[2][128 * 32];
    __shared__ __align__(16) u16 Bh[2][256 * 32], Bl[2][256 * 32];
    __shared__ float rmax[128][4];
    __shared__ float diag_s[128];
    __shared__ float wmax[8];
    const int qpath = !(blockIdx.x & 1);
    const int tile = blockIdx.x >> 1;
    const float* __restrict__ X = qpath ? Qg : Kg;
    u16* __restrict__ F = qpath ? QF : KfE;
    const int t = threadIdx.x, lane = t & 63;
    const int wid = t >> 6, wr = wid >> 2, wc = wid & 3;
    const int row0 = tile * 128;
    const int l15 = lane & 15, l4 = lane >> 4;
    const int sr = t >> 2;
    const int kcs = (((t & 3) ^ ((sr >> 1) & 3)) * 8);  // pre-swizzled src slot (B)
    const int awz = sr * 32 + (((t & 3) ^ ((sr >> 1) & 3)) * 8);  // swizzled A dst
    const int wb = wid * 512;
    const int koff = (l4 ^ ((l15 >> 1) & 3)) * 8;        // swizzled frag read
    float ss = 0.f;

    f32x4 acc[4][4];
#pragma unroll
    for (int i = 0; i < 4; ++i)
#pragma unroll
        for (int j = 0; j < 4; ++j) acc[i][j] = (f32x4){0.f, 0.f, 0.f, 0.f};

    auto stage = [&](int kt, int pb) {
        const int kk = kt * 32;
        const float4* xp = reinterpret_cast<const float4*>(&X[(size_t)(row0 + sr) * 512 + kk + (t & 3) * 8]);
        float4 v0 = xp[0], v1 = xp[1];
        const size_t gb0 = (size_t)sr * 512 + kk + kcs;
        GLDS16(Bh_g + gb0, &Bh[pb][wb]);
        GLDS16(Bl_g + gb0, &Bl[pb][wb]);
        const size_t gb1 = (size_t)(128 + sr) * 512 + kk + kcs;
        GLDS16(Bh_g + gb1, &Bh[pb][4096 + wb]);
        GLDS16(Bl_g + gb1, &Bl[pb][4096 + wb]);
        float xs[8] = {v0.x, v0.y, v0.z, v0.w, v1.x, v1.y, v1.z, v1.w};
        u32 hw[4], lw[4];
#pragma unroll
        for (int i = 0; i < 8; ++i) { xs[i] *= SCALE_; ss = fmaf(xs[i], xs[i], ss); }
#pragma unroll
        for (int i = 0; i < 4; ++i) {
            u16 h0, l0, h1, l1;
            split2(xs[2 * i], h0, l0); split2(xs[2 * i + 1], h1, l1);
            hw[i] = (u32)h0 | ((u32)h1 << 16);
            lw[i] = (u32)l0 | ((u32)l1 << 16);
        }
        *reinterpret_cast<uint4*>(&Ah[pb][awz]) = make_uint4(hw[0], hw[1], hw[2], hw[3]);
        *reinterpret_cast<uint4*>(&Al[pb][awz]) = make_uint4(lw[0], lw[1], lw[2], lw[3]);
    };

    stage(0, 0);
    __syncthreads();
    for (int kt = 0; kt < 16; ++kt) {
        const int pb = kt & 1;
        if (kt < 15) stage(kt + 1, pb ^ 1);
        bf16x8 a_h[4], a_l[4], b_h[4], b_l[4];
#pragma unroll
        for (int mf = 0; mf < 4; ++mf) {
            int r = (wr * 64 + mf * 16 + l15) * 32 + koff;
            a_h[mf] = *reinterpret_cast<const bf16x8*>(&Ah[pb][r]);
            a_l[mf] = *reinterpret_cast<const bf16x8*>(&Al[pb][r]);
        }
#pragma unroll
        for (int nf = 0; nf < 4; ++nf) {
            int r = (wc * 64 + nf * 16 + l15) * 32 + koff;
            b_h[nf] = *reinterpret_cast<const bf16x8*>(&Bh[pb][r]);
            b_l[nf] = *reinterpret_cast<const bf16x8*>(&Bl[pb][r]);
        }
#pragma unroll
        for (int mf = 0; mf < 4; ++mf)
#pragma unroll
            for (int nf = 0; nf < 4; ++nf) {
                acc[mf][nf] = __builtin_amdgcn_mfma_f32_16x16x32_bf16(a_h[mf], b_h[nf], acc[mf][nf], 0, 0, 0);
                acc[mf][nf] = __builtin_amdgcn_mfma_f32_16x16x32_bf16(a_h[mf], b_l[nf], acc[mf][nf], 0, 0, 0);
                acc[mf][nf] = __builtin_amdgcn_mfma_f32_16x16x32_bf16(a_l[mf], b_h[nf], acc[mf][nf], 0, 0, 0);
            }
        __syncthreads();
    }
    // diag: reduce ss over the 4 staging threads of each row (consecutive lanes)
    ss += __shfl_xor(ss, 1);
    ss += __shfl_xor(ss, 2);
    if ((t & 3) == 0) diag_s[sr] = 0.5f * ss;
    __syncthreads();

    if (qpath) {
        float rm[4][4];
#pragma unroll
        for (int mf = 0; mf < 4; ++mf)
#pragma unroll
            for (int r = 0; r < 4; ++r) {
                float v = fmaxf(fmaxf(acc[mf][0][r], acc[mf][1][r]),
                                fmaxf(acc[mf][2][r], acc[mf][3][r]));
#pragma unroll
                for (int off = 1; off < 16; off <<= 1) v = fmaxf(v, __shfl_xor(v, off));
                rm[mf][r] = v;
            }
        if (l15 == 0) {
#pragma unroll
            for (int mf = 0; mf < 4; ++mf)
#pragma unroll
                for (int r = 0; r < 4; ++r)
                    rmax[wr * 64 + mf * 16 + l4 * 4 + r][wc] = rm[mf][r];
        }
        __syncthreads();
#pragma unroll
        for (int mf = 0; mf < 4; ++mf)
#pragma unroll
            for (int r = 0; r < 4; ++r) {
                const int rl = wr * 64 + mf * 16 + l4 * 4 + r;
                float m4 = fmaxf(fmaxf(rmax[rl][0], rmax[rl][1]),
                                 fmaxf(rmax[rl][2], rmax[rl][3]));
                const float c = diag_s[rl] + m4;
#pragma unroll
                for (int nf = 0; nf < 4; ++nf) {
                    float f = expf(acc[mf][nf][r] - c) * RSQM_ + EPS_;
                    F[(size_t)(row0 + rl) * 256 + wc * 64 + nf * 16 + l15] = bfhi(f);
                }
            }
    } else {
        float bm = -1e30f;
#pragma unroll
        for (int mf = 0; mf < 4; ++mf)
#pragma unroll
            for (int r = 0; r < 4; ++r) {
                const int rl = wr * 64 + mf * 16 + l4 * 4 + r;
                const float c = diag_s[rl];
#pragma unroll
                for (int nf = 0; nf < 4; ++nf) {
                    float e = acc[mf][nf][r];
                    bm = fmaxf(bm, e);
                    F[(size_t)(row0 + rl) * 256 + wc * 64 + nf * 16 + l15] = bfhi(expf(e - c));
                }
            }
#pragma unroll
        for (int off = 1; off < 64; off <<= 1) bm = fmaxf(bm, __shfl_xor(bm, off));
        if (lane == 0) wmax[wid] = bm;
        __syncthreads();
        if (t == 0) {
            float m = wmax[0];
#pragma unroll
            for (int w = 1; w < 8; ++w) m = fmaxf(m, wmax[w]);
            atomicMax(&bmax[row0 >> 13], okey(m));
        }
    }
}

// transpose KfE [l][m] -> KfT [b][m][l] (bf16) + ksum partials over 64-l tiles
__global__ __launch_bounds__(256) void kx_t(const u16* __restrict__ KfE,
        u16* __restrict__ KfT, float* __restrict__ ksump) {
    const int mt = blockIdx.x & 3, lt = blockIdx.x >> 2;
    const int l0 = lt * 64, m0 = mt * 64, b = l0 >> 13;
    __shared__ u16 T[64][72];
    const int t = threadIdx.x;
    const int lrow = t >> 2, c0 = (t & 3) * 16;
    const uint4* src = reinterpret_cast<const uint4*>(&KfE[(size_t)(l0 + lrow) * 256 + m0 + c0]);
    uint4 u0 = src[0], u1 = src[1];
    *reinterpret_cast<uint4*>(&T[lrow][c0]) = u0;
    *reinterpret_cast<uint4*>(&T[lrow][c0 + 8]) = u1;
    __syncthreads();
    const int mloc = t >> 2, lc = (t & 3) * 16;
    u32 w[8];
    float s = 0.f;
#pragma unroll
    for (int j = 0; j < 8; ++j) {
        u16 a = T[lc + 2 * j][mloc], c = T[lc + 2 * j + 1][mloc];
        w[j] = (u32)a | ((u32)c << 16);
        s += bf2f(a) + bf2f(c);
    }
    size_t ob = ((size_t)(b * 256 + m0 + mloc)) * 8192 + (l0 & 8191) + lc;
    reinterpret_cast<uint4*>(&KfT[ob])[0] = make_uint4(w[0], w[1], w[2], w[3]);
    reinterpret_cast<uint4*>(&KfT[ob])[1] = make_uint4(w[4], w[5], w[6], w[7]);
    s += __shfl_xor(s, 1);
    s += __shfl_xor(s, 2);
    if ((t & 3) == 0) ksump[lt * 256 + m0 + mloc] = s;
}

// V fp32 [l][512] -> Vt bf16 [b][d][l] + vsum partials
__global__ __launch_bounds__(256) void split_vt(const float* __restrict__ V,
        u16* __restrict__ Vt, float* __restrict__ vsump) {
    const int dt = blockIdx.x & 7, lt = blockIdx.x >> 3;
    const int lg = lt * 64, b = lg >> 13, d0 = dt * 64;
    __shared__ u16 T[64][72];
    const int t = threadIdx.x;
    const int lrow = t >> 2, c0 = (t & 3) * 16;
#pragma unroll
    for (int ii = 0; ii < 4; ++ii) {
        float4 v = *reinterpret_cast<const float4*>(&V[(size_t)(lg + lrow) * 512 + d0 + c0 + ii * 4]);
        T[lrow][c0 + ii * 4 + 0] = bfhi(v.x);
        T[lrow][c0 + ii * 4 + 1] = bfhi(v.y);
        T[lrow][c0 + ii * 4 + 2] = bfhi(v.z);
        T[lrow][c0 + ii * 4 + 3] = bfhi(v.w);
    }
    __syncthreads();
    const int dloc = t >> 2, lc = (t & 3) * 16;
    u32 w[8];
    float s = 0.f;
#pragma unroll
    for (int j = 0; j < 8; ++j) {
        u16 a = T[lc + 2 * j][dloc], c = T[lc + 2 * j + 1][dloc];
        w[j] = (u32)a | ((u32)c << 16);
        s += bf2f(a) + bf2f(c);
    }
    size_t ob = ((size_t)(b * 512 + d0 + dloc)) * 8192 + (lg & 8191) + lc;
    reinterpret_cast<uint4*>(&Vt[ob])[0] = make_uint4(w[0], w[1], w[2], w[3]);
    reinterpret_cast<uint4*>(&Vt[ob])[1] = make_uint4(w[4], w[5], w[6], w[7]);
    s += __shfl_xor(s, 1);
    s += __shfl_xor(s, 2);
    if ((t & 3) == 0) vsump[lt * 512 + d0 + dloc] = s;
}

// Ksum_true[b][m] = e^{-bmax}*sum + L*EPS
__global__ __launch_bounds__(256) void ksum_red(const float* __restrict__ ksump,
        const u32* __restrict__ bmax, float* __restrict__ KsumT) {
    const int b = blockIdx.x, m = threadIdx.x;
    float s = 0.f;
    for (int j = 0; j < 128; ++j) s += ksump[(b * 128 + j) * 256 + m];
    const float g = expf(-odec(bmax[b]));
    KsumT[b * 256 + m] = g * s + (float)L_ * EPS_;
}

__global__ __launch_bounds__(256) void vsum_red(const float* __restrict__ vsump,
        float* __restrict__ Vsum) {
    const int idx = blockIdx.x * 256 + threadIdx.x;   // b*512+d
    const int b = idx >> 9, d = idx & 511;
    float s = 0.f;
    for (int j = 0; j < 128; ++j) s += vsump[(b * 128 + j) * 512 + d];
    Vsum[idx] = s;
}

// ---------------------------------------------------------------------------
// KV split-K GEMM (single bf16): kvp[ch][b][m][d] over 512-l chunks.
// Tile 128x128, 512 thr (2m x 4d waves), 2ph dbuf + swizzle, grid 512.
// ---------------------------------------------------------------------------
__global__ __launch_bounds__(512) void kv_mfma(
        const u16* __restrict__ KfT, const u16* __restrict__ Vt,
        float* __restrict__ kvp) {
    int o = (blockIdx.x & 7) * 64 + (blockIdx.x >> 3);
    const int dt = o & 3, mt = (o >> 2) & 1, ch = (o >> 3) & 15, b = o >> 7;
    const u16* Ag = KfT + ((size_t)(b * 256 + mt * 128)) * 8192 + ch * 512;
    const u16* Bg = Vt + ((size_t)(b * 512 + dt * 128)) * 8192 + ch * 512;
    __shared__ __align__(16) u16 A_[2][128 * 32], B_[2][128 * 32];
    const int t = threadIdx.x, lane = t & 63;
    const int wid = t >> 6, wr = wid >> 2, wc = wid & 3;
    const int l15 = lane & 15, l4 = lane >> 4;
    const int sr2 = t >> 2;
    const int kcs = (((t & 3) ^ ((sr2 >> 1) & 3)) * 8);
    const int koff = (l4 ^ ((l15 >> 1) & 3)) * 8;
    f32x4 acc[4][2];
#pragma unroll
    for (int i = 0; i < 4; ++i)
#pragma unroll
        for (int j = 0; j < 2; ++j) acc[i][j] = (f32x4){0.f, 0.f, 0.f, 0.f};

    auto stage = [&](int kt, int pb) {
        const size_t g = (size_t)sr2 * 8192 + kt * 32 + kcs;
        GLDS16(Ag + g, &A_[pb][wid * 512]);
        GLDS16(Bg + g, &B_[pb][wid * 512]);
    };

    stage(0, 0);
    __syncthreads();
    for (int kt = 0; kt < 16; ++kt) {
        const int pb = kt & 1;
        if (kt < 15) stage(kt + 1, pb ^ 1);
        bf16x8 a[4], bb[2];
#pragma unroll
        for (int mf = 0; mf < 4; ++mf)
            a[mf] = *reinterpret_cast<const bf16x8*>(&A_[pb][(wr * 64 + mf * 16 + l15) * 32 + koff]);
#pragma unroll
        for (int nf = 0; nf < 2; ++nf)
            bb[nf] = *reinterpret_cast<const bf16x8*>(&B_[pb][(wc * 32 + nf * 16 + l15) * 32 + koff]);
#pragma unroll
        for (int mf = 0; mf < 4; ++mf)
#pragma unroll
            for (int nf = 0; nf < 2; ++nf)
                acc[mf][nf] = __builtin_amdgcn_mfma_f32_16x16x32_bf16(a[mf], bb[nf], acc[mf][nf], 0, 0, 0);
        __syncthreads();
    }
#pragma unroll
    for (int mf = 0; mf < 4; ++mf)
#pragma unroll
        for (int r = 0; r < 4; ++r) {
            size_t oo = ((size_t)(ch * 4 + b) * 256 + mt * 128 + wr * 64 + mf * 16 + l4 * 4 + r) * 512
                        + dt * 128 + wc * 32;
#pragma unroll
            for (int nf = 0; nf < 2; ++nf)
                kvp[oo + nf * 16 + l15] = acc[mf][nf][r];
        }
}

// reduce 16 chunks + KV_adj = gscale*KV + EPS*Vsum, split hi/lo, transpose -> KVt [b][d][m]
__global__ __launch_bounds__(256) void kv_fix(const float* __restrict__ kvp,
        const u32* __restrict__ bmax, const float* __restrict__ Vsum,
        u16* __restrict__ KVth, u16* __restrict__ KVtl) {
    const int dt = blockIdx.x & 7, mt = (blockIdx.x >> 3) & 3, b = blockIdx.x >> 5;
    const int m0 = mt * 64, d0 = dt * 64;
    __shared__ u16 Th[64][72], Tl[64][72];
    const int t = threadIdx.x, mloc = t >> 2, c0 = (t & 3) * 16;
    float s[16];
#pragma unroll
    for (int j = 0; j < 16; ++j) s[j] = 0.f;
    for (int c = 0; c < 16; ++c) {
        size_t base = ((size_t)(c * 4 + b) * 256 + m0 + mloc) * 512 + d0 + c0;
#pragma unroll
        for (int ii = 0; ii < 4; ++ii) {
            float4 v = *reinterpret_cast<const float4*>(&kvp[base + ii * 4]);
            s[ii * 4 + 0] += v.x; s[ii * 4 + 1] += v.y;
            s[ii * 4 + 2] += v.z; s[ii * 4 + 3] += v.w;
        }
    }
    const float g = expf(-odec(bmax[b]));
#pragma unroll
    for (int j = 0; j < 16; ++j) {
        float v = g * s[j] + EPS_ * Vsum[b * 512 + d0 + c0 + j];
        u16 h, l; split2(v, h, l);
        Th[mloc][c0 + j] = h;
        Tl[mloc][c0 + j] = l;
    }
    __syncthreads();
    const int dloc = t >> 2, mc = (t & 3) * 16;
    size_t ob = ((size_t)(b * 512 + d0 + dloc)) * 256 + m0 + mc;
    u32 wh[8], wl[8];
#pragma unroll
    for (int j = 0; j < 8; ++j) {
        wh[j] = (u32)Th[mc + 2 * j][dloc] | ((u32)Th[mc + 2 * j + 1][dloc] << 16);
        wl[j] = (u32)Tl[mc + 2 * j][dloc] | ((u32)Tl[mc + 2 * j + 1][dloc] << 16);
    }
    reinterpret_cast<uint4*>(&KVth[ob])[0] = make_uint4(wh[0], wh[1], wh[2], wh[3]);
    reinterpret_cast<uint4*>(&KVth[ob])[1] = make_uint4(wh[4], wh[5], wh[6], wh[7]);
    reinterpret_cast<uint4*>(&KVtl[ob])[0] = make_uint4(wl[0], wl[1], wl[2], wl[3]);
    reinterpret_cast<uint4*>(&KVtl[ob])[1] = make_uint4(wl[4], wl[5], wl[6], wl[7]);
}

// Z[row] = 1/(dot(Qf_bf16, Ksum_true[b]) + eps)
__global__ __launch_bounds__(256) void z_kernel(const u16* __restrict__ QF,
        const float* __restrict__ KsumT, float* __restrict__ Z) {
    const int wid = threadIdx.x >> 6, lane = threadIdx.x & 63;
    const int row = blockIdx.x * 4 + wid;
    const int b = row >> 13;
    uint2 u = *reinterpret_cast<const uint2*>(&QF[(size_t)row * 256 + lane * 4]);
    float4 ks = *reinterpret_cast<const float4*>(&KsumT[b * 256 + lane * 4]);
    float s = bf2f((u16)(u.x & 0xffff)) * ks.x + bf2f((u16)(u.x >> 16)) * ks.y +
              bf2f((u16)(u.y & 0xffff)) * ks.z + bf2f((u16)(u.y >> 16)) * ks.w;
#pragma unroll
    for (int off = 1; off < 64; off <<= 1) s += __shfl_xor(s, off);
    if (lane == 0) Z[row] = 1.f / (s + EPS_);
}

// ---------------------------------------------------------------------------
// out GEMM: out[row][d] = Z[row]*sum_m Qf[row][m]*KVt[d][m].
// Tile 256x128, 512 thr (4r x 2d waves), 2ph dbuf + swizzle, grid 512.
// ---------------------------------------------------------------------------
__global__ __launch_bounds__(512) void out_mfma(
        const u16* __restrict__ QF, const u16* __restrict__ KVth,
        const u16* __restrict__ KVtl, const float* __restrict__ Z,
        float* __restrict__ out) {
    int o = (blockIdx.x & 7) * 64 + (blockIdx.x >> 3);
    const int dt = o & 3, rt = o >> 2;
    const int row0 = rt * 256, b = row0 >> 13;
    const u16* Ag = QF + (size_t)row0 * 256;
    const u16* Bh_g = KVth + ((size_t)(b * 512 + dt * 128)) * 256;
    const u16* Bl_g = KVtl + ((size_t)(b * 512 + dt * 128)) * 256;
    __shared__ __align__(16) u16 A_[2][256 * 32], Bh_[2][128 * 32], Bl_[2][128 * 32];
    const int t = threadIdx.x, lane = t & 63;
    const int wid = t >> 6, wr = wid >> 1, wc = wid & 1;
    const int l15 = lane & 15, l4 = lane >> 4;
    const int sr2 = t >> 2;
    const int kcs = (((t & 3) ^ ((sr2 >> 1) & 3)) * 8);
    const int koff = (l4 ^ ((l15 >> 1) & 3)) * 8;
    f32x4 acc[4][4];
#pragma unroll
    for (int i = 0; i < 4; ++i)
#pragma unroll
        for (int j = 0; j < 4; ++j) acc[i][j] = (f32x4){0.f, 0.f, 0.f, 0.f};

    auto stage = [&](int kt, int pb) {
        const size_t g0 = (size_t)sr2 * 256 + kt * 32 + kcs;
        GLDS16(Ag + g0, &A_[pb][wid * 512]);
        const size_t g1 = (size_t)(128 + sr2) * 256 + kt * 32 + kcs;
        GLDS16(Ag + g1, &A_[pb][4096 + wid * 512]);
        GLDS16(Bh_g + g0, &Bh_[pb][wid * 512]);
        GLDS16(Bl_g + g0, &Bl_[pb][wid * 512]);
    };

    stage(0, 0);
    __syncthreads();
    for (int kt = 0; kt < 8; ++kt) {
        const int pb = kt & 1;
        if (kt < 7) stage(kt + 1, pb ^ 1);
        bf16x8 a[4], bh[4], bl[4];
#pragma unroll
        for (int mf = 0; mf < 4; ++mf)
            a[mf] = *reinterpret_cast<const bf16x8*>(&A_[pb][(wr * 64 + mf * 16 + l15) * 32 + koff]);
#pragma unroll
        for (int nf = 0; nf < 4; ++nf) {
            int r = (wc * 64 + nf * 16 + l15) * 32 + koff;
            bh[nf] = *reinterpret_cast<const bf16x8*>(&Bh_[pb][r]);
            bl[nf] = *reinterpret_cast<const bf16x8*>(&Bl_[pb][r]);
        }
#pragma unroll
        for (int mf = 0; mf < 4; ++mf)
#pragma unroll
            for (int nf = 0; nf < 4; ++nf) {
                acc[mf][nf] = __builtin_amdgcn_mfma_f32_16x16x32_bf16(a[mf], bh[nf], acc[mf][nf], 0, 0, 0);
                acc[mf][nf] = __builtin_amdgcn_mfma_f32_16x16x32_bf16(a[mf], bl[nf], acc[mf][nf], 0, 0, 0);
            }
        __syncthreads();
    }
#pragma unroll
    for (int mf = 0; mf < 4; ++mf)
#pragma unroll
        for (int r = 0; r < 4; ++r) {
            const int row = row0 + wr * 64 + mf * 16 + l4 * 4 + r;
            const float z = Z[row];
#pragma unroll
            for (int nf = 0; nf < 4; ++nf)
                out[(size_t)row * 512 + dt * 128 + wc * 64 + nf * 16 + l15] = acc[mf][nf][r] * z;
        }
}

extern "C" void kernel_launch(void* const* d_in, const int* in_sizes, int n_in,
                              void* d_out, int out_size, void* d_ws, size_t ws_size,
                              hipStream_t stream) {
    const float* Q = (const float*)d_in[0];
    const float* K = (const float*)d_in[1];
    const float* V = (const float*)d_in[2];
    const float* P = (const float*)d_in[3];
    float* out = (float*)d_out;
    char* ws = (char*)d_ws;

    u16*   QF    = (u16*)(ws + 0);             // 16 MiB
    u16*   KfE   = (u16*)(ws + 16777216);      // 16 MiB (row-major exp(dash-diag))
    u16*   KfT   = (u16*)(ws + 33554432);      // 16 MiB (transposed)
    u16*   Vt    = (u16*)(ws + 50331648);      // 32 MiB
    float* kvp   = (float*)(ws + 83886080);    // 32 MiB
    u16*   KVth  = (u16*)(ws + 117440512);     // 1 MiB
    u16*   KVtl  = (u16*)(ws + 118489088);     // 1 MiB
    u16*   PH    = (u16*)(ws + 119537664);     // 256 KiB
    u16*   PL    = (u16*)(ws + 119799808);     // 256 KiB
    float* ksump = (float*)(ws + 120061952);   // 512 KiB
    float* vsump = (float*)(ws + 120586240);   // 1 MiB
    float* KsumT = (float*)(ws + 121634816);   // 4 KiB
    float* Vsum  = (float*)(ws + 121638912);   // 8 KiB
    float* Zbuf  = (float*)(ws + 121646848);   // 128 KiB
    u32*   bmax  = (u32*)(ws + 121777664);     // 16 B

    init_k<<<1, 64, 0, stream>>>(bmax);
    split_p<<<512, 256, 0, stream>>>(P, PH, PL);
    dash_all<<<512, 512, 0, stream>>>(Q, K, PH, PL, QF, KfE, bmax);
    kx_t<<<2048, 256, 0, stream>>>(KfE, KfT, ksump);
    split_vt<<<4096, 256, 0, stream>>>(V, Vt, vsump);
    ksum_red<<<4, 256, 0, stream>>>(ksump, bmax, KsumT);
    vsum_red<<<8, 256, 0, stream>>>(vsump, Vsum);
    kv_mfma<<<512, 512, 0, stream>>>(KfT, Vt, kvp);
    kv_fix<<<128, 256, 0, stream>>>(kvp, bmax, Vsum, KVth, KVtl);
    z_kernel<<<8192, 256, 0, stream>>>(QF, KsumT, Zbuf);
    out_mfma<<<512, 512, 0, stream>>>(QF, KVth, KVtl, Zbuf, out);
}

// Round 6
// 201.170 us; speedup vs baseline: 1.0070x; 1.0070x over previous
//
#include <hip/hip_runtime.h>
#include <math.h>

typedef unsigned short u16;
typedef unsigned int u32;
typedef __attribute__((ext_vector_type(8))) short bf16x8;
typedef __attribute__((ext_vector_type(4))) float f32x4;

#define SCALE_ 0.21022410381342864f   // 512^{-1/4}
#define EPS_ 1e-6f
#define RSQM_ 0.0625f                 // 1/sqrt(256)
#define L_ 8192

__device__ __forceinline__ u16 bfhi(float x) {
    u32 u = __float_as_uint(x);
    return (u16)((u + 0x7FFFu + ((u >> 16) & 1u)) >> 16);  // RNE bf16
}
__device__ __forceinline__ float bf2f(u16 h) {
    return __uint_as_float(((u32)h) << 16);
}
__device__ __forceinline__ void split2(float x, u16& h, u16& l) {
    h = bfhi(x);
    l = bfhi(x - bf2f(h));
}
__device__ __forceinline__ u32 okey(float x) {   // order-preserving float->u32
    u32 b = __float_as_uint(x);
    return (b & 0x80000000u) ? ~b : (b | 0x80000000u);
}
__device__ __forceinline__ float odec(u32 k) {
    return (k & 0x80000000u) ? __uint_as_float(k & 0x7fffffffu) : __uint_as_float(~k);
}

#define GLDS16(gsrc, ldst) \
    __builtin_amdgcn_global_load_lds((__attribute__((address_space(1))) void*)(gsrc), \
                                     (__attribute__((address_space(3))) void*)(ldst), 16, 0, 0)

__global__ void init_k(u32* __restrict__ bmax) {
    if (threadIdx.x < 4) bmax[threadIdx.x] = 0u;
}

__global__ __launch_bounds__(256) void split_p(const float* __restrict__ P,
        u16* __restrict__ Ph, u16* __restrict__ Pl) {
    int i = blockIdx.x * 256 + threadIdx.x;
    u16 h, l; split2(P[i], h, l);
    Ph[i] = h; Pl[i] = l;
}

// ---------------------------------------------------------------------------
// Fused dash GEMM. Tile 64(rows) x 256(M, full), 256 thr / 4 waves (1 wave per
// 64-col slice). Single-buffered, XOR bank swizzle, LDS = 40960 B exactly ->
// 3-4 blocks/CU for inter-block latency hiding. Grid 1024: bid<512 Q-path
// (rowmax+exp -> Qf), else K-path (exp(dash-diag) -> KfE + atomicMax bmax).
// ---------------------------------------------------------------------------
__global__ __launch_bounds__(256) void dash_all(
        const float* __restrict__ Qg, const float* __restrict__ Kg,
        const u16* __restrict__ Bh_g, const u16* __restrict__ Bl_g,
        u16* __restrict__ QF, u16* __restrict__ KfE, u32* __restrict__ bmax) {
    __shared__ __align__(16) u16 Ah[64 * 32], Al[64 * 32];     // 4 KB each
    __shared__ __align__(16) u16 Bh[256 * 32], Bl[256 * 32];   // 16 KB each
    const int qpath = (blockIdx.x < 512);
    const int tile = blockIdx.x & 511;
    const float* __restrict__ X = qpath ? Qg : Kg;
    u16* __restrict__ F = qpath ? QF : KfE;
    const int t = threadIdx.x, lane = t & 63;
    const int wid = t >> 6;                 // wave = 64-col slice wc
    const int row0 = tile * 64;
    const int l15 = lane & 15, l4 = lane >> 4;
    const int sr = t >> 2;                  // 0..63 staging row (A)
    const int awz = sr * 32 + (((t & 3) ^ ((sr >> 1) & 3)) * 8);
    const int koff = (l4 ^ ((l15 >> 1) & 3)) * 8;
    float ss = 0.f;

    f32x4 acc[4][4];
#pragma unroll
    for (int i = 0; i < 4; ++i)
#pragma unroll
        for (int j = 0; j < 4; ++j) acc[i][j] = (f32x4){0.f, 0.f, 0.f, 0.f};

    for (int kt = 0; kt < 16; ++kt) {
        const int kk = kt * 32;
        __syncthreads();
        {
            // A: 64x32 fp32 -> hi/lo bf16 in-register
            const float4* xp = reinterpret_cast<const float4*>(
                &X[(size_t)(row0 + sr) * 512 + kk + (t & 3) * 8]);
            float4 v0 = xp[0], v1 = xp[1];
            // B: 256x32 hi/lo via GLDS16, pre-swizzled source
#pragma unroll
            for (int it = 0; it < 4; ++it) {
                const int m = it * 64 + wid * 16 + (lane >> 2);
                const size_t gb = (size_t)m * 512 + kk + (((lane & 3) ^ ((m >> 1) & 3)) * 8);
                GLDS16(Bh_g + gb, Bh + it * 2048 + wid * 512);
                GLDS16(Bl_g + gb, Bl + it * 2048 + wid * 512);
            }
            float xs[8] = {v0.x, v0.y, v0.z, v0.w, v1.x, v1.y, v1.z, v1.w};
            u32 hw[4], lw[4];
#pragma unroll
            for (int i = 0; i < 8; ++i) { xs[i] *= SCALE_; ss = fmaf(xs[i], xs[i], ss); }
#pragma unroll
            for (int i = 0; i < 4; ++i) {
                u16 h0, l0, h1, l1;
                split2(xs[2 * i], h0, l0); split2(xs[2 * i + 1], h1, l1);
                hw[i] = (u32)h0 | ((u32)h1 << 16);
                lw[i] = (u32)l0 | ((u32)l1 << 16);
            }
            *reinterpret_cast<uint4*>(&Ah[awz]) = make_uint4(hw[0], hw[1], hw[2], hw[3]);
            *reinterpret_cast<uint4*>(&Al[awz]) = make_uint4(lw[0], lw[1], lw[2], lw[3]);
        }
        __syncthreads();
        bf16x8 a_h[4], a_l[4], b_h[4], b_l[4];
#pragma unroll
        for (int mf = 0; mf < 4; ++mf) {
            int r = (mf * 16 + l15) * 32 + koff;
            a_h[mf] = *reinterpret_cast<const bf16x8*>(&Ah[r]);
            a_l[mf] = *reinterpret_cast<const bf16x8*>(&Al[r]);
        }
#pragma unroll
        for (int nf = 0; nf < 4; ++nf) {
            int r = (wid * 64 + nf * 16 + l15) * 32 + koff;
            b_h[nf] = *reinterpret_cast<const bf16x8*>(&Bh[r]);
            b_l[nf] = *reinterpret_cast<const bf16x8*>(&Bl[r]);
        }
#pragma unroll
        for (int mf = 0; mf < 4; ++mf)
#pragma unroll
            for (int nf = 0; nf < 4; ++nf) {
                acc[mf][nf] = __builtin_amdgcn_mfma_f32_16x16x32_bf16(a_h[mf], b_h[nf], acc[mf][nf], 0, 0, 0);
                acc[mf][nf] = __builtin_amdgcn_mfma_f32_16x16x32_bf16(a_h[mf], b_l[nf], acc[mf][nf], 0, 0, 0);
                acc[mf][nf] = __builtin_amdgcn_mfma_f32_16x16x32_bf16(a_l[mf], b_h[nf], acc[mf][nf], 0, 0, 0);
            }
    }
    __syncthreads();   // done with Ah/Al as operand buffers; alias below
    float* rmaxp = reinterpret_cast<float*>(Ah);   // [64][4]
    float* diagp = reinterpret_cast<float*>(Al);   // [64] + wmax[4] @64

    // diag: reduce ss over the 4 staging threads of each row
    ss += __shfl_xor(ss, 1);
    ss += __shfl_xor(ss, 2);
    if ((t & 3) == 0) diagp[sr] = 0.5f * ss;

    if (qpath) {
        float rm[4][4];
#pragma unroll
        for (int mf = 0; mf < 4; ++mf)
#pragma unroll
            for (int r = 0; r < 4; ++r) {
                float v = fmaxf(fmaxf(acc[mf][0][r], acc[mf][1][r]),
                                fmaxf(acc[mf][2][r], acc[mf][3][r]));
#pragma unroll
                for (int off = 1; off < 16; off <<= 1) v = fmaxf(v, __shfl_xor(v, off));
                rm[mf][r] = v;
            }
        if (l15 == 0) {
#pragma unroll
            for (int mf = 0; mf < 4; ++mf)
#pragma unroll
                for (int r = 0; r < 4; ++r)
                    rmaxp[(mf * 16 + l4 * 4 + r) * 4 + wid] = rm[mf][r];
        }
        __syncthreads();
#pragma unroll
        for (int mf = 0; mf < 4; ++mf)
#pragma unroll
            for (int r = 0; r < 4; ++r) {
                const int rl = mf * 16 + l4 * 4 + r;
                float m4 = fmaxf(fmaxf(rmaxp[rl * 4 + 0], rmaxp[rl * 4 + 1]),
                                 fmaxf(rmaxp[rl * 4 + 2], rmaxp[rl * 4 + 3]));
                const float c = diagp[rl] + m4;
#pragma unroll
                for (int nf = 0; nf < 4; ++nf) {
                    float f = expf(acc[mf][nf][r] - c) * RSQM_ + EPS_;
                    F[(size_t)(row0 + rl) * 256 + wid * 64 + nf * 16 + l15] = bfhi(f);
                }
            }
    } else {
        __syncthreads();
        float bm = -1e30f;
#pragma unroll
        for (int mf = 0; mf < 4; ++mf)
#pragma unroll
            for (int r = 0; r < 4; ++r) {
                const int rl = mf * 16 + l4 * 4 + r;
                const float c = diagp[rl];
#pragma unroll
                for (int nf = 0; nf < 4; ++nf) {
                    float e = acc[mf][nf][r];
                    bm = fmaxf(bm, e);
                    F[(size_t)(row0 + rl) * 256 + wid * 64 + nf * 16 + l15] = bfhi(expf(e - c));
                }
            }
#pragma unroll
        for (int off = 1; off < 64; off <<= 1) bm = fmaxf(bm, __shfl_xor(bm, off));
        if (lane == 0) diagp[64 + wid] = bm;
        __syncthreads();
        if (t == 0) {
            float m = fmaxf(fmaxf(diagp[64], diagp[65]), fmaxf(diagp[66], diagp[67]));
            atomicMax(&bmax[row0 >> 13], okey(m));
        }
    }
}

// transpose KfE [l][m] -> KfT [b][m][l] (bf16) + ksum partials over 64-l tiles
__global__ __launch_bounds__(256) void kx_t(const u16* __restrict__ KfE,
        u16* __restrict__ KfT, float* __restrict__ ksump) {
    const int mt = blockIdx.x & 3, lt = blockIdx.x >> 2;
    const int l0 = lt * 64, m0 = mt * 64, b = l0 >> 13;
    __shared__ u16 T[64][72];
    const int t = threadIdx.x;
    const int lrow = t >> 2, c0 = (t & 3) * 16;
    const uint4* src = reinterpret_cast<const uint4*>(&KfE[(size_t)(l0 + lrow) * 256 + m0 + c0]);
    uint4 u0 = src[0], u1 = src[1];
    *reinterpret_cast<uint4*>(&T[lrow][c0]) = u0;
    *reinterpret_cast<uint4*>(&T[lrow][c0 + 8]) = u1;
    __syncthreads();
    const int mloc = t >> 2, lc = (t & 3) * 16;
    u32 w[8];
    float s = 0.f;
#pragma unroll
    for (int j = 0; j < 8; ++j) {
        u16 a = T[lc + 2 * j][mloc], c = T[lc + 2 * j + 1][mloc];
        w[j] = (u32)a | ((u32)c << 16);
        s += bf2f(a) + bf2f(c);
    }
    size_t ob = ((size_t)(b * 256 + m0 + mloc)) * 8192 + (l0 & 8191) + lc;
    reinterpret_cast<uint4*>(&KfT[ob])[0] = make_uint4(w[0], w[1], w[2], w[3]);
    reinterpret_cast<uint4*>(&KfT[ob])[1] = make_uint4(w[4], w[5], w[6], w[7]);
    s += __shfl_xor(s, 1);
    s += __shfl_xor(s, 2);
    if ((t & 3) == 0) ksump[lt * 256 + m0 + mloc] = s;
}

// V fp32 [l][512] -> Vt bf16 [b][d][l] + vsum partials
__global__ __launch_bounds__(256) void split_vt(const float* __restrict__ V,
        u16* __restrict__ Vt, float* __restrict__ vsump) {
    const int dt = blockIdx.x & 7, lt = blockIdx.x >> 3;
    const int lg = lt * 64, b = lg >> 13, d0 = dt * 64;
    __shared__ u16 T[64][72];
    const int t = threadIdx.x;
    const int lrow = t >> 2, c0 = (t & 3) * 16;
#pragma unroll
    for (int ii = 0; ii < 4; ++ii) {
        float4 v = *reinterpret_cast<const float4*>(&V[(size_t)(lg + lrow) * 512 + d0 + c0 + ii * 4]);
        T[lrow][c0 + ii * 4 + 0] = bfhi(v.x);
        T[lrow][c0 + ii * 4 + 1] = bfhi(v.y);
        T[lrow][c0 + ii * 4 + 2] = bfhi(v.z);
        T[lrow][c0 + ii * 4 + 3] = bfhi(v.w);
    }
    __syncthreads();
    const int dloc = t >> 2, lc = (t & 3) * 16;
    u32 w[8];
    float s = 0.f;
#pragma unroll
    for (int j = 0; j < 8; ++j) {
        u16 a = T[lc + 2 * j][dloc], c = T[lc + 2 * j + 1][dloc];
        w[j] = (u32)a | ((u32)c << 16);
        s += bf2f(a) + bf2f(c);
    }
    size_t ob = ((size_t)(b * 512 + d0 + dloc)) * 8192 + (lg & 8191) + lc;
    reinterpret_cast<uint4*>(&Vt[ob])[0] = make_uint4(w[0], w[1], w[2], w[3]);
    reinterpret_cast<uint4*>(&Vt[ob])[1] = make_uint4(w[4], w[5], w[6], w[7]);
    s += __shfl_xor(s, 1);
    s += __shfl_xor(s, 2);
    if ((t & 3) == 0) vsump[lt * 512 + d0 + dloc] = s;
}

// Ksum_true[b][m] = e^{-bmax}*sum + L*EPS
__global__ __launch_bounds__(256) void ksum_red(const float* __restrict__ ksump,
        const u32* __restrict__ bmax, float* __restrict__ KsumT) {
    const int b = blockIdx.x, m = threadIdx.x;
    float s = 0.f;
    for (int j = 0; j < 128; ++j) s += ksump[(b * 128 + j) * 256 + m];
    const float g = expf(-odec(bmax[b]));
    KsumT[b * 256 + m] = g * s + (float)L_ * EPS_;
}

__global__ __launch_bounds__(256) void vsum_red(const float* __restrict__ vsump,
        float* __restrict__ Vsum) {
    const int idx = blockIdx.x * 256 + threadIdx.x;   // b*512+d
    const int b = idx >> 9, d = idx & 511;
    float s = 0.f;
    for (int j = 0; j < 128; ++j) s += vsump[(b * 128 + j) * 512 + d];
    Vsum[idx] = s;
}

// ---------------------------------------------------------------------------
// KV split-K GEMM (single bf16): kvp[ch][b][m][d] over 256-l chunks (32 chunks).
// Tile 128x128, 256 thr / 4 waves (2m x 2d), single-buffer 16 KB, grid 1024.
// ---------------------------------------------------------------------------
__global__ __launch_bounds__(256) void kv_mfma(
        const u16* __restrict__ KfT, const u16* __restrict__ Vt,
        float* __restrict__ kvp) {
    int o = (blockIdx.x & 7) * 128 + (blockIdx.x >> 3);
    const int dt = o & 3, mt = (o >> 2) & 1, ch = (o >> 3) & 31, b = o >> 8;
    const u16* Ag = KfT + ((size_t)(b * 256 + mt * 128)) * 8192 + ch * 256;
    const u16* Bg = Vt + ((size_t)(b * 512 + dt * 128)) * 8192 + ch * 256;
    __shared__ __align__(16) u16 A_[128 * 32], B_[128 * 32];
    const int t = threadIdx.x, lane = t & 63;
    const int wid = t >> 6, wr = wid >> 1, wc = wid & 1;
    const int l15 = lane & 15, l4 = lane >> 4;
    const int koff = (l4 ^ ((l15 >> 1) & 3)) * 8;
    f32x4 acc[4][4];
#pragma unroll
    for (int i = 0; i < 4; ++i)
#pragma unroll
        for (int j = 0; j < 4; ++j) acc[i][j] = (f32x4){0.f, 0.f, 0.f, 0.f};

    for (int kt = 0; kt < 8; ++kt) {
        __syncthreads();
#pragma unroll
        for (int it = 0; it < 2; ++it) {
            const int row = it * 64 + wid * 16 + (lane >> 2);
            const size_t g = (size_t)row * 8192 + kt * 32 + (((lane & 3) ^ ((row >> 1) & 3)) * 8);
            GLDS16(Ag + g, A_ + it * 2048 + wid * 512);
            GLDS16(Bg + g, B_ + it * 2048 + wid * 512);
        }
        __syncthreads();
        bf16x8 a[4], bb[4];
#pragma unroll
        for (int mf = 0; mf < 4; ++mf)
            a[mf] = *reinterpret_cast<const bf16x8*>(&A_[(wr * 64 + mf * 16 + l15) * 32 + koff]);
#pragma unroll
        for (int nf = 0; nf < 4; ++nf)
            bb[nf] = *reinterpret_cast<const bf16x8*>(&B_[(wc * 64 + nf * 16 + l15) * 32 + koff]);
#pragma unroll
        for (int mf = 0; mf < 4; ++mf)
#pragma unroll
            for (int nf = 0; nf < 4; ++nf)
                acc[mf][nf] = __builtin_amdgcn_mfma_f32_16x16x32_bf16(a[mf], bb[nf], acc[mf][nf], 0, 0, 0);
    }
#pragma unroll
    for (int mf = 0; mf < 4; ++mf)
#pragma unroll
        for (int r = 0; r < 4; ++r) {
            size_t oo = ((size_t)(ch * 4 + b) * 256 + mt * 128 + wr * 64 + mf * 16 + l4 * 4 + r) * 512
                        + dt * 128 + wc * 64;
#pragma unroll
            for (int nf = 0; nf < 4; ++nf)
                kvp[oo + nf * 16 + l15] = acc[mf][nf][r];
        }
}

// reduce 32 chunks + KV_adj = gscale*KV + EPS*Vsum, split hi/lo, transpose -> KVt [b][d][m]
__global__ __launch_bounds__(256) void kv_fix(const float* __restrict__ kvp,
        const u32* __restrict__ bmax, const float* __restrict__ Vsum,
        u16* __restrict__ KVth, u16* __restrict__ KVtl) {
    const int dt = blockIdx.x & 7, mt = (blockIdx.x >> 3) & 3, b = blockIdx.x >> 5;
    const int m0 = mt * 64, d0 = dt * 64;
    __shared__ u16 Th[64][72], Tl[64][72];
    const int t = threadIdx.x, mloc = t >> 2, c0 = (t & 3) * 16;
    float s[16];
#pragma unroll
    for (int j = 0; j < 16; ++j) s[j] = 0.f;
    for (int c = 0; c < 32; ++c) {
        size_t base = ((size_t)(c * 4 + b) * 256 + m0 + mloc) * 512 + d0 + c0;
#pragma unroll
        for (int ii = 0; ii < 4; ++ii) {
            float4 v = *reinterpret_cast<const float4*>(&kvp[base + ii * 4]);
            s[ii * 4 + 0] += v.x; s[ii * 4 + 1] += v.y;
            s[ii * 4 + 2] += v.z; s[ii * 4 + 3] += v.w;
        }
    }
    const float g = expf(-odec(bmax[b]));
#pragma unroll
    for (int j = 0; j < 16; ++j) {
        float v = g * s[j] + EPS_ * Vsum[b * 512 + d0 + c0 + j];
        u16 h, l; split2(v, h, l);
        Th[mloc][c0 + j] = h;
        Tl[mloc][c0 + j] = l;
    }
    __syncthreads();
    const int dloc = t >> 2, mc = (t & 3) * 16;
    size_t ob = ((size_t)(b * 512 + d0 + dloc)) * 256 + m0 + mc;
    u32 wh[8], wl[8];
#pragma unroll
    for (int j = 0; j < 8; ++j) {
        wh[j] = (u32)Th[mc + 2 * j][dloc] | ((u32)Th[mc + 2 * j + 1][dloc] << 16);
        wl[j] = (u32)Tl[mc + 2 * j][dloc] | ((u32)Tl[mc + 2 * j + 1][dloc] << 16);
    }
    reinterpret_cast<uint4*>(&KVth[ob])[0] = make_uint4(wh[0], wh[1], wh[2], wh[3]);
    reinterpret_cast<uint4*>(&KVth[ob])[1] = make_uint4(wh[4], wh[5], wh[6], wh[7]);
    reinterpret_cast<uint4*>(&KVtl[ob])[0] = make_uint4(wl[0], wl[1], wl[2], wl[3]);
    reinterpret_cast<uint4*>(&KVtl[ob])[1] = make_uint4(wl[4], wl[5], wl[6], wl[7]);
}

// Z[row] = 1/(dot(Qf_bf16, Ksum_true[b]) + eps)
__global__ __launch_bounds__(256) void z_kernel(const u16* __restrict__ QF,
        const float* __restrict__ KsumT, float* __restrict__ Z) {
    const int wid = threadIdx.x >> 6, lane = threadIdx.x & 63;
    const int row = blockIdx.x * 4 + wid;
    const int b = row >> 13;
    uint2 u = *reinterpret_cast<const uint2*>(&QF[(size_t)row * 256 + lane * 4]);
    float4 ks = *reinterpret_cast<const float4*>(&KsumT[b * 256 + lane * 4]);
    float s = bf2f((u16)(u.x & 0xffff)) * ks.x + bf2f((u16)(u.x >> 16)) * ks.y +
              bf2f((u16)(u.y & 0xffff)) * ks.z + bf2f((u16)(u.y >> 16)) * ks.w;
#pragma unroll
    for (int off = 1; off < 64; off <<= 1) s += __shfl_xor(s, off);
    if (lane == 0) Z[row] = 1.f / (s + EPS_);
}

// ---------------------------------------------------------------------------
// out GEMM: out[row][d] = Z[row]*sum_m Qf[row][m]*KVt[d][m].
// Tile 128x128, 256 thr / 4 waves (2r x 2d), single-buffer 24 KB, grid 1024.
// ---------------------------------------------------------------------------
__global__ __launch_bounds__(256) void out_mfma(
        const u16* __restrict__ QF, const u16* __restrict__ KVth,
        const u16* __restrict__ KVtl, const float* __restrict__ Z,
        float* __restrict__ out) {
    int o = (blockIdx.x & 7) * 128 + (blockIdx.x >> 3);
    const int dt = o & 3, rt = o >> 2;
    const int row0 = rt * 128, b = row0 >> 13;
    const u16* Ag = QF + (size_t)row0 * 256;
    const u16* Bh_g = KVth + ((size_t)(b * 512 + dt * 128)) * 256;
    const u16* Bl_g = KVtl + ((size_t)(b * 512 + dt * 128)) * 256;
    __shared__ __align__(16) u16 A_[128 * 32], Bh_[128 * 32], Bl_[128 * 32];
    const int t = threadIdx.x, lane = t & 63;
    const int wid = t >> 6, wr = wid >> 1, wc = wid & 1;
    const int l15 = lane & 15, l4 = lane >> 4;
    const int koff = (l4 ^ ((l15 >> 1) & 3)) * 8;
    f32x4 acc[4][4];
#pragma unroll
    for (int i = 0; i < 4; ++i)
#pragma unroll
        for (int j = 0; j < 4; ++j) acc[i][j] = (f32x4){0.f, 0.f, 0.f, 0.f};

    for (int kt = 0; kt < 8; ++kt) {
        __syncthreads();
#pragma unroll
        for (int it = 0; it < 2; ++it) {
            const int row = it * 64 + wid * 16 + (lane >> 2);
            const size_t g = (size_t)row * 256 + kt * 32 + (((lane & 3) ^ ((row >> 1) & 3)) * 8);
            GLDS16(Ag + g, A_ + it * 2048 + wid * 512);
            GLDS16(Bh_g + g, Bh_ + it * 2048 + wid * 512);
            GLDS16(Bl_g + g, Bl_ + it * 2048 + wid * 512);
        }
        __syncthreads();
        bf16x8 a[4], bh[4], bl[4];
#pragma unroll
        for (int mf = 0; mf < 4; ++mf)
            a[mf] = *reinterpret_cast<const bf16x8*>(&A_[(wr * 64 + mf * 16 + l15) * 32 + koff]);
#pragma unroll
        for (int nf = 0; nf < 4; ++nf) {
            int r = (wc * 64 + nf * 16 + l15) * 32 + koff;
            bh[nf] = *reinterpret_cast<const bf16x8*>(&Bh_[r]);
            bl[nf] = *reinterpret_cast<const bf16x8*>(&Bl_[r]);
        }
#pragma unroll
        for (int mf = 0; mf < 4; ++mf)
#pragma unroll
            for (int nf = 0; nf < 4; ++nf) {
                acc[mf][nf] = __builtin_amdgcn_mfma_f32_16x16x32_bf16(a[mf], bh[nf], acc[mf][nf], 0, 0, 0);
                acc[mf][nf] = __builtin_amdgcn_mfma_f32_16x16x32_bf16(a[mf], bl[nf], acc[mf][nf], 0, 0, 0);
            }
    }
#pragma unroll
    for (int mf = 0; mf < 4; ++mf)
#pragma unroll
        for (int r = 0; r < 4; ++r) {
            const int row = row0 + wr * 64 + mf * 16 + l4 * 4 + r;
            const float z = Z[row];
#pragma unroll
            for (int nf = 0; nf < 4; ++nf)
                out[(size_t)row * 512 + dt * 128 + wc * 64 + nf * 16 + l15] = acc[mf][nf][r] * z;
        }
}

extern "C" void kernel_launch(void* const* d_in, const int* in_sizes, int n_in,
                              void* d_out, int out_size, void* d_ws, size_t ws_size,
                              hipStream_t stream) {
    const float* Q = (const float*)d_in[0];
    const float* K = (const float*)d_in[1];
    const float* V = (const float*)d_in[2];
    const float* P = (const float*)d_in[3];
    float* out = (float*)d_out;
    char* ws = (char*)d_ws;

    u16*   QF    = (u16*)(ws + 0);             // 16 MiB
    u16*   KfE   = (u16*)(ws + 16777216);      // 16 MiB
    u16*   KfT   = (u16*)(ws + 33554432);      // 16 MiB
    u16*   Vt    = (u16*)(ws + 50331648);      // 32 MiB
    float* kvp   = (float*)(ws + 83886080);    // 64 MiB (32 chunks)
    u16*   KVth  = (u16*)(ws + 150994944);     // 1 MiB
    u16*   KVtl  = (u16*)(ws + 152043520);     // 1 MiB
    u16*   PH    = (u16*)(ws + 153092096);     // 256 KiB
    u16*   PL    = (u16*)(ws + 153354240);     // 256 KiB
    float* ksump = (float*)(ws + 153616384);   // 512 KiB
    float* vsump = (float*)(ws + 154140672);   // 1 MiB
    float* KsumT = (float*)(ws + 155189248);   // 4 KiB
    float* Vsum  = (float*)(ws + 155193344);   // 8 KiB
    float* Zbuf  = (float*)(ws + 155201536);   // 128 KiB
    u32*   bmax  = (u32*)(ws + 155332608);     // 16 B

    init_k<<<1, 64, 0, stream>>>(bmax);
    split_p<<<512, 256, 0, stream>>>(P, PH, PL);
    dash_all<<<1024, 256, 0, stream>>>(Q, K, PH, PL, QF, KfE, bmax);
    kx_t<<<2048, 256, 0, stream>>>(KfE, KfT, ksump);
    split_vt<<<4096, 256, 0, stream>>>(V, Vt, vsump);
    ksum_red<<<4, 256, 0, stream>>>(ksump, bmax, KsumT);
    vsum_red<<<8, 256, 0, stream>>>(vsump, Vsum);
    kv_mfma<<<1024, 256, 0, stream>>>(KfT, Vt, kvp);
    kv_fix<<<128, 256, 0, stream>>>(kvp, bmax, Vsum, KVth, KVtl);
    z_kernel<<<8192, 256, 0, stream>>>(QF, KsumT, Zbuf);
    out_mfma<<<1024, 256, 0, stream>>>(QF, KVth, KVtl, Zbuf, out);
}

// Round 7
// 181.610 us; speedup vs baseline: 1.1155x; 1.1077x over previous
//
#include <hip/hip_runtime.h>
#include <math.h>

typedef unsigned short u16;
typedef unsigned int u32;
typedef __attribute__((ext_vector_type(8))) short bf16x8;
typedef __attribute__((ext_vector_type(4))) float f32x4;

#define SCALE_ 0.21022410381342864f   // 512^{-1/4}
#define EPS_ 1e-6f
#define RSQM_ 0.0625f                 // 1/sqrt(256)
#define L_ 8192

__device__ __forceinline__ float bf2f(u16 h) {
    return __uint_as_float(((u32)h) << 16);
}
// pack two fp32 -> two RNE bf16 in one u32 (lo=x0, hi=x1)
__device__ __forceinline__ u32 cvtpk(float x0, float x1) {
    u32 w;
    asm("v_cvt_pk_bf16_f32 %0, %1, %2" : "=v"(w) : "v"(x0), "v"(x1));
    return w;
}
// hi/lo split of a pair: hw = bf16(x0,x1), lw = bf16(residuals)
__device__ __forceinline__ void split_pk(float x0, float x1, u32& hw, u32& lw) {
    hw = cvtpk(x0, x1);
    float h0 = __uint_as_float(hw << 16);
    float h1 = __uint_as_float(hw & 0xffff0000u);
    lw = cvtpk(x0 - h0, x1 - h1);
}
__device__ __forceinline__ u32 okey(float x) {   // order-preserving float->u32
    u32 b = __float_as_uint(x);
    return (b & 0x80000000u) ? ~b : (b | 0x80000000u);
}
__device__ __forceinline__ float odec(u32 k) {
    return (k & 0x80000000u) ? __uint_as_float(k & 0x7fffffffu) : __uint_as_float(~k);
}

#define GLDS16(gsrc, ldst) \
    __builtin_amdgcn_global_load_lds((__attribute__((address_space(1))) void*)(gsrc), \
                                     (__attribute__((address_space(3))) void*)(ldst), 16, 0, 0)

__global__ void init_k(u32* __restrict__ bmax) {
    if (threadIdx.x < 4) bmax[threadIdx.x] = 0u;
}

__global__ __launch_bounds__(256) void split_p(const float* __restrict__ P,
        u16* __restrict__ Ph, u16* __restrict__ Pl) {
    int i = (blockIdx.x * 256 + threadIdx.x) * 2;
    u32 hw, lw;
    split_pk(P[i], P[i + 1], hw, lw);
    *reinterpret_cast<u32*>(&Ph[i]) = hw;
    *reinterpret_cast<u32*>(&Pl[i]) = lw;
}

// ---------------------------------------------------------------------------
// Fused dash GEMM. Tile 64(rows) x 256(M full), 256 thr / 4 waves. Single
// buffer, XOR swizzle, LDS 40 KB -> 3 blocks/CU. Grid 1024: bid<512 Q-path
// (rowmax+exp -> QF row-major), else K-path (exp(dash-diag) -> KfT TRANSPOSED
// [b][m][l] + ksum partials + atomicMax bmax). kx_t kernel deleted.
// ---------------------------------------------------------------------------
__global__ __launch_bounds__(256) void dash_all(
        const float* __restrict__ Qg, const float* __restrict__ Kg,
        const u16* __restrict__ Bh_g, const u16* __restrict__ Bl_g,
        u16* __restrict__ QF, u16* __restrict__ KfT, float* __restrict__ ksump,
        u32* __restrict__ bmax) {
    __shared__ __align__(16) u16 Ah[64 * 32], Al[64 * 32];     // 4 KB each
    __shared__ __align__(16) u16 Bh[256 * 32], Bl[256 * 32];   // 16 KB each
    const int qpath = (blockIdx.x < 512);
    const int tile = blockIdx.x & 511;
    const float* __restrict__ X = qpath ? Qg : Kg;
    const int t = threadIdx.x, lane = t & 63;
    const int wid = t >> 6;                 // wave = 64-col (m) slice
    const int row0 = tile * 64;
    const int l15 = lane & 15, l4 = lane >> 4;
    const int sr = t >> 2;                  // 0..63 staging row (A)
    const int awz = sr * 32 + (((t & 3) ^ ((sr >> 1) & 3)) * 8);
    const int koff = (l4 ^ ((l15 >> 1) & 3)) * 8;
    float ss = 0.f;

    // hoisted staging pointers (advance 32 elems per K-step)
    const float* xp = &X[(size_t)(row0 + sr) * 512 + (t & 3) * 8];
    const u16* bsrch[4];
    const u16* bsrcl[4];
#pragma unroll
    for (int it = 0; it < 4; ++it) {
        const int m = it * 64 + wid * 16 + (lane >> 2);
        const int swz = ((lane & 3) ^ ((m >> 1) & 3)) * 8;
        bsrch[it] = Bh_g + (size_t)m * 512 + swz;
        bsrcl[it] = Bl_g + (size_t)m * 512 + swz;
    }

    f32x4 acc[4][4];
#pragma unroll
    for (int i = 0; i < 4; ++i)
#pragma unroll
        for (int j = 0; j < 4; ++j) acc[i][j] = (f32x4){0.f, 0.f, 0.f, 0.f};

    for (int kt = 0; kt < 16; ++kt) {
        __syncthreads();
        {
            float4 v0 = *reinterpret_cast<const float4*>(xp);
            float4 v1 = *reinterpret_cast<const float4*>(xp + 4);
            xp += 32;
#pragma unroll
            for (int it = 0; it < 4; ++it) {
                GLDS16(bsrch[it], Bh + it * 2048 + wid * 512);
                GLDS16(bsrcl[it], Bl + it * 2048 + wid * 512);
                bsrch[it] += 32; bsrcl[it] += 32;
            }
            float xs[8] = {v0.x * SCALE_, v0.y * SCALE_, v0.z * SCALE_, v0.w * SCALE_,
                           v1.x * SCALE_, v1.y * SCALE_, v1.z * SCALE_, v1.w * SCALE_};
#pragma unroll
            for (int i = 0; i < 8; ++i) ss = fmaf(xs[i], xs[i], ss);
            u32 hw[4], lw[4];
#pragma unroll
            for (int i = 0; i < 4; ++i) split_pk(xs[2 * i], xs[2 * i + 1], hw[i], lw[i]);
            *reinterpret_cast<uint4*>(&Ah[awz]) = make_uint4(hw[0], hw[1], hw[2], hw[3]);
            *reinterpret_cast<uint4*>(&Al[awz]) = make_uint4(lw[0], lw[1], lw[2], lw[3]);
        }
        __syncthreads();
        bf16x8 a_h[4], a_l[4], b_h[4], b_l[4];
#pragma unroll
        for (int mf = 0; mf < 4; ++mf) {
            int r = (mf * 16 + l15) * 32 + koff;
            a_h[mf] = *reinterpret_cast<const bf16x8*>(&Ah[r]);
            a_l[mf] = *reinterpret_cast<const bf16x8*>(&Al[r]);
        }
#pragma unroll
        for (int nf = 0; nf < 4; ++nf) {
            int r = (wid * 64 + nf * 16 + l15) * 32 + koff;
            b_h[nf] = *reinterpret_cast<const bf16x8*>(&Bh[r]);
            b_l[nf] = *reinterpret_cast<const bf16x8*>(&Bl[r]);
        }
#pragma unroll
        for (int mf = 0; mf < 4; ++mf)
#pragma unroll
            for (int nf = 0; nf < 4; ++nf) {
                acc[mf][nf] = __builtin_amdgcn_mfma_f32_16x16x32_bf16(a_h[mf], b_h[nf], acc[mf][nf], 0, 0, 0);
                acc[mf][nf] = __builtin_amdgcn_mfma_f32_16x16x32_bf16(a_h[mf], b_l[nf], acc[mf][nf], 0, 0, 0);
                acc[mf][nf] = __builtin_amdgcn_mfma_f32_16x16x32_bf16(a_l[mf], b_h[nf], acc[mf][nf], 0, 0, 0);
            }
    }
    __syncthreads();   // operand buffers done; alias for epilogue scratch
    float* rmaxp = reinterpret_cast<float*>(Ah);   // [64][4]
    float* diagp = reinterpret_cast<float*>(Al);   // [64] + wmax[4] @64

    ss += __shfl_xor(ss, 1);
    ss += __shfl_xor(ss, 2);
    if ((t & 3) == 0) diagp[sr] = 0.5f * ss;

    if (qpath) {
        float rm[4][4];
#pragma unroll
        for (int mf = 0; mf < 4; ++mf)
#pragma unroll
            for (int r = 0; r < 4; ++r) {
                float v = fmaxf(fmaxf(acc[mf][0][r], acc[mf][1][r]),
                                fmaxf(acc[mf][2][r], acc[mf][3][r]));
#pragma unroll
                for (int off = 1; off < 16; off <<= 1) v = fmaxf(v, __shfl_xor(v, off));
                rm[mf][r] = v;
            }
        if (l15 == 0) {
#pragma unroll
            for (int mf = 0; mf < 4; ++mf)
#pragma unroll
                for (int r = 0; r < 4; ++r)
                    rmaxp[(mf * 16 + l4 * 4 + r) * 4 + wid] = rm[mf][r];
        }
        __syncthreads();
#pragma unroll
        for (int mf = 0; mf < 4; ++mf)
#pragma unroll
            for (int r = 0; r < 4; ++r) {
                const int rl = mf * 16 + l4 * 4 + r;
                float m4 = fmaxf(fmaxf(rmaxp[rl * 4 + 0], rmaxp[rl * 4 + 1]),
                                 fmaxf(rmaxp[rl * 4 + 2], rmaxp[rl * 4 + 3]));
                const float c = diagp[rl] + m4;
                float f0 = expf(acc[mf][0][r] - c) * RSQM_ + EPS_;
                float f1 = expf(acc[mf][1][r] - c) * RSQM_ + EPS_;
                float f2 = expf(acc[mf][2][r] - c) * RSQM_ + EPS_;
                float f3 = expf(acc[mf][3][r] - c) * RSQM_ + EPS_;
                u32 w01 = cvtpk(f0, f1), w23 = cvtpk(f2, f3);
                size_t o = (size_t)(row0 + rl) * 256 + wid * 64 + l15;
                QF[o]      = (u16)w01;
                QF[o + 16] = (u16)(w01 >> 16);
                QF[o + 32] = (u16)w23;
                QF[o + 48] = (u16)(w23 >> 16);
            }
    } else {
        __syncthreads();
        const int b = row0 >> 13;
        const int ll = row0 & 8191;
        float bm = -1e30f;
        float s[4] = {0.f, 0.f, 0.f, 0.f};
#pragma unroll
        for (int nf = 0; nf < 4; ++nf) {
            const size_t mb = ((size_t)(b * 256 + wid * 64 + nf * 16 + l15)) * 8192 + ll + l4 * 4;
#pragma unroll
            for (int mf = 0; mf < 4; ++mf) {
                const float c = diagp[mf * 16 + l4 * 4];   // note: c varies with r!
                float e0 = acc[mf][nf][0], e1 = acc[mf][nf][1];
                float e2 = acc[mf][nf][2], e3 = acc[mf][nf][3];
                bm = fmaxf(fmaxf(bm, fmaxf(e0, e1)), fmaxf(e2, e3));
                float x0 = expf(e0 - diagp[mf * 16 + l4 * 4 + 0]);
                float x1 = expf(e1 - diagp[mf * 16 + l4 * 4 + 1]);
                float x2 = expf(e2 - diagp[mf * 16 + l4 * 4 + 2]);
                float x3 = expf(e3 - diagp[mf * 16 + l4 * 4 + 3]);
                s[nf] += (x0 + x1) + (x2 + x3);
                uint2 w = make_uint2(cvtpk(x0, x1), cvtpk(x2, x3));
                *reinterpret_cast<uint2*>(&KfT[mb + mf * 16]) = w;
                (void)c;
            }
        }
        // ksum partials: reduce over l4 groups (lanes stride 16)
#pragma unroll
        for (int nf = 0; nf < 4; ++nf) {
            s[nf] += __shfl_xor(s[nf], 16);
            s[nf] += __shfl_xor(s[nf], 32);
        }
        if (l4 == 0) {
#pragma unroll
            for (int nf = 0; nf < 4; ++nf)
                ksump[tile * 256 + wid * 64 + nf * 16 + l15] = s[nf];
        }
#pragma unroll
        for (int off = 1; off < 64; off <<= 1) bm = fmaxf(bm, __shfl_xor(bm, off));
        if (lane == 0) diagp[64 + wid] = bm;
        __syncthreads();
        if (t == 0) {
            float m = fmaxf(fmaxf(diagp[64], diagp[65]), fmaxf(diagp[66], diagp[67]));
            atomicMax(&bmax[b], okey(m));
        }
    }
}

// V fp32 [l][512] -> Vt bf16 [b][d][l] + vsum partials
__global__ __launch_bounds__(256) void split_vt(const float* __restrict__ V,
        u16* __restrict__ Vt, float* __restrict__ vsump) {
    const int dt = blockIdx.x & 7, lt = blockIdx.x >> 3;
    const int lg = lt * 64, b = lg >> 13, d0 = dt * 64;
    __shared__ u16 T[64][72];
    const int t = threadIdx.x;
    const int lrow = t >> 2, c0 = (t & 3) * 16;
#pragma unroll
    for (int ii = 0; ii < 4; ++ii) {
        float4 v = *reinterpret_cast<const float4*>(&V[(size_t)(lg + lrow) * 512 + d0 + c0 + ii * 4]);
        *reinterpret_cast<u32*>(&T[lrow][c0 + ii * 4 + 0]) = cvtpk(v.x, v.y);
        *reinterpret_cast<u32*>(&T[lrow][c0 + ii * 4 + 2]) = cvtpk(v.z, v.w);
    }
    __syncthreads();
    const int dloc = t >> 2, lc = (t & 3) * 16;
    u32 w[8];
    float s = 0.f;
#pragma unroll
    for (int j = 0; j < 8; ++j) {
        u16 a = T[lc + 2 * j][dloc], c = T[lc + 2 * j + 1][dloc];
        w[j] = (u32)a | ((u32)c << 16);
        s += bf2f(a) + bf2f(c);
    }
    size_t ob = ((size_t)(b * 512 + d0 + dloc)) * 8192 + (lg & 8191) + lc;
    reinterpret_cast<uint4*>(&Vt[ob])[0] = make_uint4(w[0], w[1], w[2], w[3]);
    reinterpret_cast<uint4*>(&Vt[ob])[1] = make_uint4(w[4], w[5], w[6], w[7]);
    s += __shfl_xor(s, 1);
    s += __shfl_xor(s, 2);
    if ((t & 3) == 0) vsump[lt * 512 + d0 + dloc] = s;
}

// Ksum_true[b][m] = e^{-bmax}*sum + L*EPS
__global__ __launch_bounds__(256) void ksum_red(const float* __restrict__ ksump,
        const u32* __restrict__ bmax, float* __restrict__ KsumT) {
    const int b = blockIdx.x, m = threadIdx.x;
    float s = 0.f;
    for (int j = 0; j < 128; ++j) s += ksump[(b * 128 + j) * 256 + m];
    const float g = expf(-odec(bmax[b]));
    KsumT[b * 256 + m] = g * s + (float)L_ * EPS_;
}

__global__ __launch_bounds__(256) void vsum_red(const float* __restrict__ vsump,
        float* __restrict__ Vsum) {
    const int idx = blockIdx.x * 256 + threadIdx.x;   // b*512+d
    const int b = idx >> 9, d = idx & 511;
    float s = 0.f;
    for (int j = 0; j < 128; ++j) s += vsump[(b * 128 + j) * 512 + d];
    Vsum[idx] = s;
}

// ---------------------------------------------------------------------------
// KV split-K GEMM (single bf16): kvp[ch][b][m][d] over 512-l chunks (16).
// Tile 128x128, 256 thr / 4 waves (2m x 2d), single-buffer 16 KB, grid 512.
// ---------------------------------------------------------------------------
__global__ __launch_bounds__(256) void kv_mfma(
        const u16* __restrict__ KfT, const u16* __restrict__ Vt,
        float* __restrict__ kvp) {
    int o = (blockIdx.x & 7) * 64 + (blockIdx.x >> 3);
    const int dt = o & 3, mt = (o >> 2) & 1, ch = (o >> 3) & 15, b = o >> 7;
    const u16* Ag = KfT + ((size_t)(b * 256 + mt * 128)) * 8192 + ch * 512;
    const u16* Bg = Vt + ((size_t)(b * 512 + dt * 128)) * 8192 + ch * 512;
    __shared__ __align__(16) u16 A_[128 * 32], B_[128 * 32];
    const int t = threadIdx.x, lane = t & 63;
    const int wid = t >> 6, wr = wid >> 1, wc = wid & 1;
    const int l15 = lane & 15, l4 = lane >> 4;
    const int koff = (l4 ^ ((l15 >> 1) & 3)) * 8;
    const u16* asrc[2];
    const u16* bsrc[2];
#pragma unroll
    for (int it = 0; it < 2; ++it) {
        const int row = it * 64 + wid * 16 + (lane >> 2);
        const int swz = ((lane & 3) ^ ((row >> 1) & 3)) * 8;
        asrc[it] = Ag + (size_t)row * 8192 + swz;
        bsrc[it] = Bg + (size_t)row * 8192 + swz;
    }
    f32x4 acc[4][4];
#pragma unroll
    for (int i = 0; i < 4; ++i)
#pragma unroll
        for (int j = 0; j < 4; ++j) acc[i][j] = (f32x4){0.f, 0.f, 0.f, 0.f};

    for (int kt = 0; kt < 16; ++kt) {
        __syncthreads();
#pragma unroll
        for (int it = 0; it < 2; ++it) {
            GLDS16(asrc[it], A_ + it * 2048 + wid * 512);
            GLDS16(bsrc[it], B_ + it * 2048 + wid * 512);
            asrc[it] += 32; bsrc[it] += 32;
        }
        __syncthreads();
        bf16x8 a[4], bb[4];
#pragma unroll
        for (int mf = 0; mf < 4; ++mf)
            a[mf] = *reinterpret_cast<const bf16x8*>(&A_[(wr * 64 + mf * 16 + l15) * 32 + koff]);
#pragma unroll
        for (int nf = 0; nf < 4; ++nf)
            bb[nf] = *reinterpret_cast<const bf16x8*>(&B_[(wc * 64 + nf * 16 + l15) * 32 + koff]);
#pragma unroll
        for (int mf = 0; mf < 4; ++mf)
#pragma unroll
            for (int nf = 0; nf < 4; ++nf)
                acc[mf][nf] = __builtin_amdgcn_mfma_f32_16x16x32_bf16(a[mf], bb[nf], acc[mf][nf], 0, 0, 0);
    }
#pragma unroll
    for (int mf = 0; mf < 4; ++mf)
#pragma unroll
        for (int r = 0; r < 4; ++r) {
            size_t oo = ((size_t)(ch * 4 + b) * 256 + mt * 128 + wr * 64 + mf * 16 + l4 * 4 + r) * 512
                        + dt * 128 + wc * 64;
#pragma unroll
            for (int nf = 0; nf < 4; ++nf)
                kvp[oo + nf * 16 + l15] = acc[mf][nf][r];
        }
}

// reduce 16 chunks + KV_adj = g*KV + EPS*Vsum, split hi/lo, transpose -> KVt [b][d][m]
__global__ __launch_bounds__(256) void kv_fix(const float* __restrict__ kvp,
        const u32* __restrict__ bmax, const float* __restrict__ Vsum,
        u16* __restrict__ KVth, u16* __restrict__ KVtl) {
    const int dt = blockIdx.x & 7, mt = (blockIdx.x >> 3) & 3, b = blockIdx.x >> 5;
    const int m0 = mt * 64, d0 = dt * 64;
    __shared__ u16 Th[64][72], Tl[64][72];
    const int t = threadIdx.x, mloc = t >> 2, c0 = (t & 3) * 16;
    float s[16];
#pragma unroll
    for (int j = 0; j < 16; ++j) s[j] = 0.f;
    for (int c = 0; c < 16; ++c) {
        size_t base = ((size_t)(c * 4 + b) * 256 + m0 + mloc) * 512 + d0 + c0;
#pragma unroll
        for (int ii = 0; ii < 4; ++ii) {
            float4 v = *reinterpret_cast<const float4*>(&kvp[base + ii * 4]);
            s[ii * 4 + 0] += v.x; s[ii * 4 + 1] += v.y;
            s[ii * 4 + 2] += v.z; s[ii * 4 + 3] += v.w;
        }
    }
    const float g = expf(-odec(bmax[b]));
#pragma unroll
    for (int j = 0; j < 16; j += 2) {
        float v0 = g * s[j]     + EPS_ * Vsum[b * 512 + d0 + c0 + j];
        float v1 = g * s[j + 1] + EPS_ * Vsum[b * 512 + d0 + c0 + j + 1];
        u32 hw, lw; split_pk(v0, v1, hw, lw);
        *reinterpret_cast<u32*>(&Th[mloc][c0 + j]) = hw;
        *reinterpret_cast<u32*>(&Tl[mloc][c0 + j]) = lw;
    }
    __syncthreads();
    const int dloc = t >> 2, mc = (t & 3) * 16;
    size_t ob = ((size_t)(b * 512 + d0 + dloc)) * 256 + m0 + mc;
    u32 wh[8], wl[8];
#pragma unroll
    for (int j = 0; j < 8; ++j) {
        wh[j] = (u32)Th[mc + 2 * j][dloc] | ((u32)Th[mc + 2 * j + 1][dloc] << 16);
        wl[j] = (u32)Tl[mc + 2 * j][dloc] | ((u32)Tl[mc + 2 * j + 1][dloc] << 16);
    }
    reinterpret_cast<uint4*>(&KVth[ob])[0] = make_uint4(wh[0], wh[1], wh[2], wh[3]);
    reinterpret_cast<uint4*>(&KVth[ob])[1] = make_uint4(wh[4], wh[5], wh[6], wh[7]);
    reinterpret_cast<uint4*>(&KVtl[ob])[0] = make_uint4(wl[0], wl[1], wl[2], wl[3]);
    reinterpret_cast<uint4*>(&KVtl[ob])[1] = make_uint4(wl[4], wl[5], wl[6], wl[7]);
}

// Z[row] = 1/(dot(Qf_bf16, Ksum_true[b]) + eps)
__global__ __launch_bounds__(256) void z_kernel(const u16* __restrict__ QF,
        const float* __restrict__ KsumT, float* __restrict__ Z) {
    const int wid = threadIdx.x >> 6, lane = threadIdx.x & 63;
    const int row = blockIdx.x * 4 + wid;
    const int b = row >> 13;
    uint2 u = *reinterpret_cast<const uint2*>(&QF[(size_t)row * 256 + lane * 4]);
    float4 ks = *reinterpret_cast<const float4*>(&KsumT[b * 256 + lane * 4]);
    float s = bf2f((u16)(u.x & 0xffff)) * ks.x + bf2f((u16)(u.x >> 16)) * ks.y +
              bf2f((u16)(u.y & 0xffff)) * ks.z + bf2f((u16)(u.y >> 16)) * ks.w;
#pragma unroll
    for (int off = 1; off < 64; off <<= 1) s += __shfl_xor(s, off);
    if (lane == 0) Z[row] = 1.f / (s + EPS_);
}

// ---------------------------------------------------------------------------
// out GEMM: out[row][d] = Z[row]*sum_m Qf[row][m]*KVt[d][m].
// Tile 128x128, 256 thr / 4 waves (2r x 2d), single-buffer 24 KB, grid 1024.
// ---------------------------------------------------------------------------
__global__ __launch_bounds__(256) void out_mfma(
        const u16* __restrict__ QF, const u16* __restrict__ KVth,
        const u16* __restrict__ KVtl, const float* __restrict__ Z,
        float* __restrict__ out) {
    int o = (blockIdx.x & 7) * 128 + (blockIdx.x >> 3);
    const int dt = o & 3, rt = o >> 2;
    const int row0 = rt * 128, b = row0 >> 13;
    const u16* Ag = QF + (size_t)row0 * 256;
    const u16* Bh_g = KVth + ((size_t)(b * 512 + dt * 128)) * 256;
    const u16* Bl_g = KVtl + ((size_t)(b * 512 + dt * 128)) * 256;
    __shared__ __align__(16) u16 A_[128 * 32], Bh_[128 * 32], Bl_[128 * 32];
    const int t = threadIdx.x, lane = t & 63;
    const int wid = t >> 6, wr = wid >> 1, wc = wid & 1;
    const int l15 = lane & 15, l4 = lane >> 4;
    const int koff = (l4 ^ ((l15 >> 1) & 3)) * 8;
    const u16* asrc[2];
    const u16* bhsrc[2];
    const u16* blsrc[2];
#pragma unroll
    for (int it = 0; it < 2; ++it) {
        const int row = it * 64 + wid * 16 + (lane >> 2);
        const int swz = ((lane & 3) ^ ((row >> 1) & 3)) * 8;
        asrc[it]  = Ag + (size_t)row * 256 + swz;
        bhsrc[it] = Bh_g + (size_t)row * 256 + swz;
        blsrc[it] = Bl_g + (size_t)row * 256 + swz;
    }
    f32x4 acc[4][4];
#pragma unroll
    for (int i = 0; i < 4; ++i)
#pragma unroll
        for (int j = 0; j < 4; ++j) acc[i][j] = (f32x4){0.f, 0.f, 0.f, 0.f};

    for (int kt = 0; kt < 8; ++kt) {
        __syncthreads();
#pragma unroll
        for (int it = 0; it < 2; ++it) {
            GLDS16(asrc[it], A_ + it * 2048 + wid * 512);
            GLDS16(bhsrc[it], Bh_ + it * 2048 + wid * 512);
            GLDS16(blsrc[it], Bl_ + it * 2048 + wid * 512);
            asrc[it] += 32; bhsrc[it] += 32; blsrc[it] += 32;
        }
        __syncthreads();
        bf16x8 a[4], bh[4], bl[4];
#pragma unroll
        for (int mf = 0; mf < 4; ++mf)
            a[mf] = *reinterpret_cast<const bf16x8*>(&A_[(wr * 64 + mf * 16 + l15) * 32 + koff]);
#pragma unroll
        for (int nf = 0; nf < 4; ++nf) {
            int r = (wc * 64 + nf * 16 + l15) * 32 + koff;
            bh[nf] = *reinterpret_cast<const bf16x8*>(&Bh_[r]);
            bl[nf] = *reinterpret_cast<const bf16x8*>(&Bl_[r]);
        }
#pragma unroll
        for (int mf = 0; mf < 4; ++mf)
#pragma unroll
            for (int nf = 0; nf < 4; ++nf) {
                acc[mf][nf] = __builtin_amdgcn_mfma_f32_16x16x32_bf16(a[mf], bh[nf], acc[mf][nf], 0, 0, 0);
                acc[mf][nf] = __builtin_amdgcn_mfma_f32_16x16x32_bf16(a[mf], bl[nf], acc[mf][nf], 0, 0, 0);
            }
    }
#pragma unroll
    for (int mf = 0; mf < 4; ++mf)
#pragma unroll
        for (int r = 0; r < 4; ++r) {
            const int row = row0 + wr * 64 + mf * 16 + l4 * 4 + r;
            const float z = Z[row];
#pragma unroll
            for (int nf = 0; nf < 4; ++nf)
                out[(size_t)row * 512 + dt * 128 + wc * 64 + nf * 16 + l15] = acc[mf][nf][r] * z;
        }
}

extern "C" void kernel_launch(void* const* d_in, const int* in_sizes, int n_in,
                              void* d_out, int out_size, void* d_ws, size_t ws_size,
                              hipStream_t stream) {
    const float* Q = (const float*)d_in[0];
    const float* K = (const float*)d_in[1];
    const float* V = (const float*)d_in[2];
    const float* P = (const float*)d_in[3];
    float* out = (float*)d_out;
    char* ws = (char*)d_ws;

    u16*   QF    = (u16*)(ws + 0);             // 16 MiB
    u16*   KfT   = (u16*)(ws + 16777216);      // 16 MiB (transposed, fused)
    u16*   Vt    = (u16*)(ws + 33554432);      // 32 MiB
    float* kvp   = (float*)(ws + 67108864);    // 32 MiB (16 chunks)
    u16*   KVth  = (u16*)(ws + 100663296);     // 1 MiB
    u16*   KVtl  = (u16*)(ws + 101711872);     // 1 MiB
    u16*   PH    = (u16*)(ws + 102760448);     // 256 KiB
    u16*   PL    = (u16*)(ws + 103022592);     // 256 KiB
    float* ksump = (float*)(ws + 103284736);   // 512 KiB
    float* vsump = (float*)(ws + 103809024);   // 1 MiB
    float* KsumT = (float*)(ws + 104857600);   // 4 KiB
    float* Vsum  = (float*)(ws + 104861696);   // 8 KiB
    float* Zbuf  = (float*)(ws + 104869888);   // 128 KiB
    u32*   bmax  = (u32*)(ws + 105000960);     // 16 B

    init_k<<<1, 64, 0, stream>>>(bmax);
    split_p<<<256, 256, 0, stream>>>(P, PH, PL);
    dash_all<<<1024, 256, 0, stream>>>(Q, K, PH, PL, QF, KfT, ksump, bmax);
    split_vt<<<4096, 256, 0, stream>>>(V, Vt, vsump);
    ksum_red<<<4, 256, 0, stream>>>(ksump, bmax, KsumT);
    vsum_red<<<8, 256, 0, stream>>>(vsump, Vsum);
    kv_mfma<<<512, 256, 0, stream>>>(KfT, Vt, kvp);
    kv_fix<<<128, 256, 0, stream>>>(kvp, bmax, Vsum, KVth, KVtl);
    z_kernel<<<8192, 256, 0, stream>>>(QF, KsumT, Zbuf);
    out_mfma<<<1024, 256, 0, stream>>>(QF, KVth, KVtl, Zbuf, out);
}

// Round 8
// 174.676 us; speedup vs baseline: 1.1598x; 1.0397x over previous
//
#include <hip/hip_runtime.h>
#include <math.h>

typedef unsigned short u16;
typedef unsigned int u32;
typedef __attribute__((ext_vector_type(8))) short bf16x8;
typedef __attribute__((ext_vector_type(4))) float f32x4;

#define SCALE_ 0.21022410381342864f   // 512^{-1/4}
#define EPS_ 1e-6f
#define RSQM_ 0.0625f                 // 1/sqrt(256)
#define L_ 8192

__device__ __forceinline__ float bf2f(u16 h) {
    return __uint_as_float(((u32)h) << 16);
}
// pack two fp32 -> two RNE bf16 in one u32 (lo=x0, hi=x1)
__device__ __forceinline__ u32 cvtpk(float x0, float x1) {
    u32 w;
    asm("v_cvt_pk_bf16_f32 %0, %1, %2" : "=v"(w) : "v"(x0), "v"(x1));
    return w;
}
// hi/lo split of a pair: hw = bf16(x0,x1), lw = bf16(residuals)
__device__ __forceinline__ void split_pk(float x0, float x1, u32& hw, u32& lw) {
    hw = cvtpk(x0, x1);
    float h0 = __uint_as_float(hw << 16);
    float h1 = __uint_as_float(hw & 0xffff0000u);
    lw = cvtpk(x0 - h0, x1 - h1);
}
__device__ __forceinline__ u32 okey(float x) {   // order-preserving float->u32
    u32 b = __float_as_uint(x);
    return (b & 0x80000000u) ? ~b : (b | 0x80000000u);
}
__device__ __forceinline__ float odec(u32 k) {
    return (k & 0x80000000u) ? __uint_as_float(k & 0x7fffffffu) : __uint_as_float(~k);
}

#define GLDS16(gsrc, ldst) \
    __builtin_amdgcn_global_load_lds((__attribute__((address_space(1))) void*)(gsrc), \
                                     (__attribute__((address_space(3))) void*)(ldst), 16, 0, 0)

// P pre-scaled by SCALE_, hi/lo split; block 0 also zeroes bmax.
__global__ __launch_bounds__(256) void split_p(const float* __restrict__ P,
        u16* __restrict__ Ph, u16* __restrict__ Pl, u32* __restrict__ bmax) {
    if (blockIdx.x == 0 && threadIdx.x < 4) bmax[threadIdx.x] = 0u;
    int i = (blockIdx.x * 256 + threadIdx.x) * 2;
    u32 hw, lw;
    split_pk(P[i] * SCALE_, P[i + 1] * SCALE_, hw, lw);
    *reinterpret_cast<u32*>(&Ph[i]) = hw;
    *reinterpret_cast<u32*>(&Pl[i]) = lw;
}

// ---------------------------------------------------------------------------
// Fused dash GEMM. Tile 64(rows) x 256(M full), 256 thr / 4 waves. Single
// buffer, XOR swizzle, LDS 40 KB -> 3 blocks/CU. Grid 1024 interleaved:
// even bid = Q-path (rowmax+exp -> QF row-major), odd = K-path
// (exp(dash-diag) -> KfT transposed [b][m][l] + ksum partials + bmax).
// A fp32 loads PREFETCHED one K-step ahead (T14): latency hides under MFMA.
// ---------------------------------------------------------------------------
__global__ __launch_bounds__(256) void dash_all(
        const float* __restrict__ Qg, const float* __restrict__ Kg,
        const u16* __restrict__ Bh_g, const u16* __restrict__ Bl_g,
        u16* __restrict__ QF, u16* __restrict__ KfT, float* __restrict__ ksump,
        u32* __restrict__ bmax) {
    __shared__ __align__(16) u16 Ah[64 * 32], Al[64 * 32];     // 4 KB each
    __shared__ __align__(16) u16 Bh[256 * 32], Bl[256 * 32];   // 16 KB each
    const int qpath = !(blockIdx.x & 1);
    const int tile = blockIdx.x >> 1;
    const float* __restrict__ X = qpath ? Qg : Kg;
    const int t = threadIdx.x, lane = t & 63;
    const int wid = t >> 6;                 // wave = 64-col (m) slice
    const int row0 = tile * 64;
    const int l15 = lane & 15, l4 = lane >> 4;
    const int sr = t >> 2;                  // 0..63 staging row (A)
    const int awz = sr * 32 + (((t & 3) ^ ((sr >> 1) & 3)) * 8);
    const int koff = (l4 ^ ((l15 >> 1) & 3)) * 8;
    float ss = 0.f;

    // hoisted staging pointers (advance 32 elems per K-step)
    const float* xp = &X[(size_t)(row0 + sr) * 512 + (t & 3) * 8];
    const u16* bsrch[4];
    const u16* bsrcl[4];
#pragma unroll
    for (int it = 0; it < 4; ++it) {
        const int m = it * 64 + wid * 16 + (lane >> 2);
        const int swz = ((lane & 3) ^ ((m >> 1) & 3)) * 8;
        bsrch[it] = Bh_g + (size_t)m * 512 + swz;
        bsrcl[it] = Bl_g + (size_t)m * 512 + swz;
    }

    f32x4 acc[4][4];
#pragma unroll
    for (int i = 0; i < 4; ++i)
#pragma unroll
        for (int j = 0; j < 4; ++j) acc[i][j] = (f32x4){0.f, 0.f, 0.f, 0.f};

    // prefetched A registers for the CURRENT K-step
    float4 v0 = *reinterpret_cast<const float4*>(xp);
    float4 v1 = *reinterpret_cast<const float4*>(xp + 4);

    for (int kt = 0; kt < 16; ++kt) {
        __syncthreads();
        {
#pragma unroll
            for (int it = 0; it < 4; ++it) {
                GLDS16(bsrch[it], Bh + it * 2048 + wid * 512);
                GLDS16(bsrcl[it], Bl + it * 2048 + wid * 512);
                bsrch[it] += 32; bsrcl[it] += 32;
            }
            float xs[8] = {v0.x, v0.y, v0.z, v0.w, v1.x, v1.y, v1.z, v1.w};
#pragma unroll
            for (int i = 0; i < 8; ++i) ss = fmaf(xs[i], xs[i], ss);
            u32 hw[4], lw[4];
#pragma unroll
            for (int i = 0; i < 4; ++i) split_pk(xs[2 * i], xs[2 * i + 1], hw[i], lw[i]);
            *reinterpret_cast<uint4*>(&Ah[awz]) = make_uint4(hw[0], hw[1], hw[2], hw[3]);
            *reinterpret_cast<uint4*>(&Al[awz]) = make_uint4(lw[0], lw[1], lw[2], lw[3]);
            // issue next K-step's A loads NOW; latency covered by MFMA phase
            xp = (kt < 15) ? xp + 32 : xp;
            v0 = *reinterpret_cast<const float4*>(xp);
            v1 = *reinterpret_cast<const float4*>(xp + 4);
        }
        __syncthreads();
        bf16x8 a_h[4], a_l[4], b_h[4], b_l[4];
#pragma unroll
        for (int mf = 0; mf < 4; ++mf) {
            int r = (mf * 16 + l15) * 32 + koff;
            a_h[mf] = *reinterpret_cast<const bf16x8*>(&Ah[r]);
            a_l[mf] = *reinterpret_cast<const bf16x8*>(&Al[r]);
        }
#pragma unroll
        for (int nf = 0; nf < 4; ++nf) {
            int r = (wid * 64 + nf * 16 + l15) * 32 + koff;
            b_h[nf] = *reinterpret_cast<const bf16x8*>(&Bh[r]);
            b_l[nf] = *reinterpret_cast<const bf16x8*>(&Bl[r]);
        }
#pragma unroll
        for (int mf = 0; mf < 4; ++mf)
#pragma unroll
            for (int nf = 0; nf < 4; ++nf) {
                acc[mf][nf] = __builtin_amdgcn_mfma_f32_16x16x32_bf16(a_h[mf], b_h[nf], acc[mf][nf], 0, 0, 0);
                acc[mf][nf] = __builtin_amdgcn_mfma_f32_16x16x32_bf16(a_h[mf], b_l[nf], acc[mf][nf], 0, 0, 0);
                acc[mf][nf] = __builtin_amdgcn_mfma_f32_16x16x32_bf16(a_l[mf], b_h[nf], acc[mf][nf], 0, 0, 0);
            }
    }
    __syncthreads();   // operand buffers done; alias for epilogue scratch
    float* rmaxp = reinterpret_cast<float*>(Ah);   // [64][4]
    float* diagp = reinterpret_cast<float*>(Al);   // [64] + wmax[4] @64

    ss += __shfl_xor(ss, 1);
    ss += __shfl_xor(ss, 2);
    if ((t & 3) == 0) diagp[sr] = 0.5f * SCALE_ * SCALE_ * ss;

    if (qpath) {
        float rm[4][4];
#pragma unroll
        for (int mf = 0; mf < 4; ++mf)
#pragma unroll
            for (int r = 0; r < 4; ++r) {
                float v = fmaxf(fmaxf(acc[mf][0][r], acc[mf][1][r]),
                                fmaxf(acc[mf][2][r], acc[mf][3][r]));
#pragma unroll
                for (int off = 1; off < 16; off <<= 1) v = fmaxf(v, __shfl_xor(v, off));
                rm[mf][r] = v;
            }
        if (l15 == 0) {
#pragma unroll
            for (int mf = 0; mf < 4; ++mf)
#pragma unroll
                for (int r = 0; r < 4; ++r)
                    rmaxp[(mf * 16 + l4 * 4 + r) * 4 + wid] = rm[mf][r];
        }
        __syncthreads();
#pragma unroll
        for (int mf = 0; mf < 4; ++mf)
#pragma unroll
            for (int r = 0; r < 4; ++r) {
                const int rl = mf * 16 + l4 * 4 + r;
                float m4 = fmaxf(fmaxf(rmaxp[rl * 4 + 0], rmaxp[rl * 4 + 1]),
                                 fmaxf(rmaxp[rl * 4 + 2], rmaxp[rl * 4 + 3]));
                const float c = diagp[rl] + m4;
                float f0 = expf(acc[mf][0][r] - c) * RSQM_ + EPS_;
                float f1 = expf(acc[mf][1][r] - c) * RSQM_ + EPS_;
                float f2 = expf(acc[mf][2][r] - c) * RSQM_ + EPS_;
                float f3 = expf(acc[mf][3][r] - c) * RSQM_ + EPS_;
                u32 w01 = cvtpk(f0, f1), w23 = cvtpk(f2, f3);
                size_t o = (size_t)(row0 + rl) * 256 + wid * 64 + l15;
                QF[o]      = (u16)w01;
                QF[o + 16] = (u16)(w01 >> 16);
                QF[o + 32] = (u16)w23;
                QF[o + 48] = (u16)(w23 >> 16);
            }
    } else {
        __syncthreads();
        const int b = row0 >> 13;
        const int ll = row0 & 8191;
        float bm = -1e30f;
        float s[4] = {0.f, 0.f, 0.f, 0.f};
#pragma unroll
        for (int nf = 0; nf < 4; ++nf) {
            const size_t mb = ((size_t)(b * 256 + wid * 64 + nf * 16 + l15)) * 8192 + ll + l4 * 4;
#pragma unroll
            for (int mf = 0; mf < 4; ++mf) {
                float e0 = acc[mf][nf][0], e1 = acc[mf][nf][1];
                float e2 = acc[mf][nf][2], e3 = acc[mf][nf][3];
                bm = fmaxf(fmaxf(bm, fmaxf(e0, e1)), fmaxf(e2, e3));
                float x0 = expf(e0 - diagp[mf * 16 + l4 * 4 + 0]);
                float x1 = expf(e1 - diagp[mf * 16 + l4 * 4 + 1]);
                float x2 = expf(e2 - diagp[mf * 16 + l4 * 4 + 2]);
                float x3 = expf(e3 - diagp[mf * 16 + l4 * 4 + 3]);
                s[nf] += (x0 + x1) + (x2 + x3);
                uint2 w = make_uint2(cvtpk(x0, x1), cvtpk(x2, x3));
                *reinterpret_cast<uint2*>(&KfT[mb + mf * 16]) = w;
            }
        }
        // ksum partials: reduce over l4 groups (lanes stride 16)
#pragma unroll
        for (int nf = 0; nf < 4; ++nf) {
            s[nf] += __shfl_xor(s[nf], 16);
            s[nf] += __shfl_xor(s[nf], 32);
        }
        if (l4 == 0) {
#pragma unroll
            for (int nf = 0; nf < 4; ++nf)
                ksump[tile * 256 + wid * 64 + nf * 16 + l15] = s[nf];
        }
#pragma unroll
        for (int off = 1; off < 64; off <<= 1) bm = fmaxf(bm, __shfl_xor(bm, off));
        if (lane == 0) diagp[64 + wid] = bm;
        __syncthreads();
        if (t == 0) {
            float m = fmaxf(fmaxf(diagp[64], diagp[65]), fmaxf(diagp[66], diagp[67]));
            atomicMax(&bmax[b], okey(m));
        }
    }
}

// V fp32 [l][512] -> Vt bf16 [b][d][l] + vsum partials
__global__ __launch_bounds__(256) void split_vt(const float* __restrict__ V,
        u16* __restrict__ Vt, float* __restrict__ vsump) {
    const int dt = blockIdx.x & 7, lt = blockIdx.x >> 3;
    const int lg = lt * 64, b = lg >> 13, d0 = dt * 64;
    __shared__ u16 T[64][72];
    const int t = threadIdx.x;
    const int lrow = t >> 2, c0 = (t & 3) * 16;
#pragma unroll
    for (int ii = 0; ii < 4; ++ii) {
        float4 v = *reinterpret_cast<const float4*>(&V[(size_t)(lg + lrow) * 512 + d0 + c0 + ii * 4]);
        *reinterpret_cast<u32*>(&T[lrow][c0 + ii * 4 + 0]) = cvtpk(v.x, v.y);
        *reinterpret_cast<u32*>(&T[lrow][c0 + ii * 4 + 2]) = cvtpk(v.z, v.w);
    }
    __syncthreads();
    const int dloc = t >> 2, lc = (t & 3) * 16;
    u32 w[8];
    float s = 0.f;
#pragma unroll
    for (int j = 0; j < 8; ++j) {
        u16 a = T[lc + 2 * j][dloc], c = T[lc + 2 * j + 1][dloc];
        w[j] = (u32)a | ((u32)c << 16);
        s += bf2f(a) + bf2f(c);
    }
    size_t ob = ((size_t)(b * 512 + d0 + dloc)) * 8192 + (lg & 8191) + lc;
    reinterpret_cast<uint4*>(&Vt[ob])[0] = make_uint4(w[0], w[1], w[2], w[3]);
    reinterpret_cast<uint4*>(&Vt[ob])[1] = make_uint4(w[4], w[5], w[6], w[7]);
    s += __shfl_xor(s, 1);
    s += __shfl_xor(s, 2);
    if ((t & 3) == 0) vsump[lt * 512 + d0 + dloc] = s;
}

// Ksum_true[b][m] = e^{-bmax}*sum + L*EPS
__global__ __launch_bounds__(256) void ksum_red(const float* __restrict__ ksump,
        const u32* __restrict__ bmax, float* __restrict__ KsumT) {
    const int b = blockIdx.x, m = threadIdx.x;
    float s = 0.f;
    for (int j = 0; j < 128; ++j) s += ksump[(b * 128 + j) * 256 + m];
    const float g = expf(-odec(bmax[b]));
    KsumT[b * 256 + m] = g * s + (float)L_ * EPS_;
}

__global__ __launch_bounds__(256) void vsum_red(const float* __restrict__ vsump,
        float* __restrict__ Vsum) {
    const int idx = blockIdx.x * 256 + threadIdx.x;   // b*512+d
    const int b = idx >> 9, d = idx & 511;
    float s = 0.f;
    for (int j = 0; j < 128; ++j) s += vsump[(b * 128 + j) * 512 + d];
    Vsum[idx] = s;
}

// ---------------------------------------------------------------------------
// KV split-K GEMM (single bf16): kvp[ch][b][m][d] over 512-l chunks (16).
// Tile 128x128, 256 thr / 4 waves (2m x 2d), single-buffer 16 KB, grid 512.
// ---------------------------------------------------------------------------
__global__ __launch_bounds__(256) void kv_mfma(
        const u16* __restrict__ KfT, const u16* __restrict__ Vt,
        float* __restrict__ kvp) {
    int o = (blockIdx.x & 7) * 64 + (blockIdx.x >> 3);
    const int dt = o & 3, mt = (o >> 2) & 1, ch = (o >> 3) & 15, b = o >> 7;
    const u16* Ag = KfT + ((size_t)(b * 256 + mt * 128)) * 8192 + ch * 512;
    const u16* Bg = Vt + ((size_t)(b * 512 + dt * 128)) * 8192 + ch * 512;
    __shared__ __align__(16) u16 A_[128 * 32], B_[128 * 32];
    const int t = threadIdx.x, lane = t & 63;
    const int wid = t >> 6, wr = wid >> 1, wc = wid & 1;
    const int l15 = lane & 15, l4 = lane >> 4;
    const int koff = (l4 ^ ((l15 >> 1) & 3)) * 8;
    const u16* asrc[2];
    const u16* bsrc[2];
#pragma unroll
    for (int it = 0; it < 2; ++it) {
        const int row = it * 64 + wid * 16 + (lane >> 2);
        const int swz = ((lane & 3) ^ ((row >> 1) & 3)) * 8;
        asrc[it] = Ag + (size_t)row * 8192 + swz;
        bsrc[it] = Bg + (size_t)row * 8192 + swz;
    }
    f32x4 acc[4][4];
#pragma unroll
    for (int i = 0; i < 4; ++i)
#pragma unroll
        for (int j = 0; j < 4; ++j) acc[i][j] = (f32x4){0.f, 0.f, 0.f, 0.f};

    for (int kt = 0; kt < 16; ++kt) {
        __syncthreads();
#pragma unroll
        for (int it = 0; it < 2; ++it) {
            GLDS16(asrc[it], A_ + it * 2048 + wid * 512);
            GLDS16(bsrc[it], B_ + it * 2048 + wid * 512);
            asrc[it] += 32; bsrc[it] += 32;
        }
        __syncthreads();
        bf16x8 a[4], bb[4];
#pragma unroll
        for (int mf = 0; mf < 4; ++mf)
            a[mf] = *reinterpret_cast<const bf16x8*>(&A_[(wr * 64 + mf * 16 + l15) * 32 + koff]);
#pragma unroll
        for (int nf = 0; nf < 4; ++nf)
            bb[nf] = *reinterpret_cast<const bf16x8*>(&B_[(wc * 64 + nf * 16 + l15) * 32 + koff]);
#pragma unroll
        for (int mf = 0; mf < 4; ++mf)
#pragma unroll
            for (int nf = 0; nf < 4; ++nf)
                acc[mf][nf] = __builtin_amdgcn_mfma_f32_16x16x32_bf16(a[mf], bb[nf], acc[mf][nf], 0, 0, 0);
    }
#pragma unroll
    for (int mf = 0; mf < 4; ++mf)
#pragma unroll
        for (int r = 0; r < 4; ++r) {
            size_t oo = ((size_t)(ch * 4 + b) * 256 + mt * 128 + wr * 64 + mf * 16 + l4 * 4 + r) * 512
                        + dt * 128 + wc * 64;
#pragma unroll
            for (int nf = 0; nf < 4; ++nf)
                kvp[oo + nf * 16 + l15] = acc[mf][nf][r];
        }
}

// reduce 16 chunks + KV_adj = g*KV + EPS*Vsum, split hi/lo, transpose -> KVt [b][d][m]
__global__ __launch_bounds__(256) void kv_fix(const float* __restrict__ kvp,
        const u32* __restrict__ bmax, const float* __restrict__ Vsum,
        u16* __restrict__ KVth, u16* __restrict__ KVtl) {
    const int dt = blockIdx.x & 7, mt = (blockIdx.x >> 3) & 3, b = blockIdx.x >> 5;
    const int m0 = mt * 64, d0 = dt * 64;
    __shared__ u16 Th[64][72], Tl[64][72];
    const int t = threadIdx.x, mloc = t >> 2, c0 = (t & 3) * 16;
    float s[16];
#pragma unroll
    for (int j = 0; j < 16; ++j) s[j] = 0.f;
    for (int c = 0; c < 16; ++c) {
        size_t base = ((size_t)(c * 4 + b) * 256 + m0 + mloc) * 512 + d0 + c0;
#pragma unroll
        for (int ii = 0; ii < 4; ++ii) {
            float4 v = *reinterpret_cast<const float4*>(&kvp[base + ii * 4]);
            s[ii * 4 + 0] += v.x; s[ii * 4 + 1] += v.y;
            s[ii * 4 + 2] += v.z; s[ii * 4 + 3] += v.w;
        }
    }
    const float g = expf(-odec(bmax[b]));
#pragma unroll
    for (int j = 0; j < 16; j += 2) {
        float v0 = g * s[j]     + EPS_ * Vsum[b * 512 + d0 + c0 + j];
        float v1 = g * s[j + 1] + EPS_ * Vsum[b * 512 + d0 + c0 + j + 1];
        u32 hw, lw; split_pk(v0, v1, hw, lw);
        *reinterpret_cast<u32*>(&Th[mloc][c0 + j]) = hw;
        *reinterpret_cast<u32*>(&Tl[mloc][c0 + j]) = lw;
    }
    __syncthreads();
    const int dloc = t >> 2, mc = (t & 3) * 16;
    size_t ob = ((size_t)(b * 512 + d0 + dloc)) * 256 + m0 + mc;
    u32 wh[8], wl[8];
#pragma unroll
    for (int j = 0; j < 8; ++j) {
        wh[j] = (u32)Th[mc + 2 * j][dloc] | ((u32)Th[mc + 2 * j + 1][dloc] << 16);
        wl[j] = (u32)Tl[mc + 2 * j][dloc] | ((u32)Tl[mc + 2 * j + 1][dloc] << 16);
    }
    reinterpret_cast<uint4*>(&KVth[ob])[0] = make_uint4(wh[0], wh[1], wh[2], wh[3]);
    reinterpret_cast<uint4*>(&KVth[ob])[1] = make_uint4(wh[4], wh[5], wh[6], wh[7]);
    reinterpret_cast<uint4*>(&KVtl[ob])[0] = make_uint4(wl[0], wl[1], wl[2], wl[3]);
    reinterpret_cast<uint4*>(&KVtl[ob])[1] = make_uint4(wl[4], wl[5], wl[6], wl[7]);
}

// Z[row] = 1/(dot(Qf_bf16, Ksum_true[b]) + eps)
__global__ __launch_bounds__(256) void z_kernel(const u16* __restrict__ QF,
        const float* __restrict__ KsumT, float* __restrict__ Z) {
    const int wid = threadIdx.x >> 6, lane = threadIdx.x & 63;
    const int row = blockIdx.x * 4 + wid;
    const int b = row >> 13;
    uint2 u = *reinterpret_cast<const uint2*>(&QF[(size_t)row * 256 + lane * 4]);
    float4 ks = *reinterpret_cast<const float4*>(&KsumT[b * 256 + lane * 4]);
    float s = bf2f((u16)(u.x & 0xffff)) * ks.x + bf2f((u16)(u.x >> 16)) * ks.y +
              bf2f((u16)(u.y & 0xffff)) * ks.z + bf2f((u16)(u.y >> 16)) * ks.w;
#pragma unroll
    for (int off = 1; off < 64; off <<= 1) s += __shfl_xor(s, off);
    if (lane == 0) Z[row] = 1.f / (s + EPS_);
}

// ---------------------------------------------------------------------------
// out GEMM: out[row][d] = Z[row]*sum_m Qf[row][m]*KVt[d][m].
// Tile 128x128, 256 thr / 4 waves (2r x 2d), single-buffer 24 KB, grid 1024.
// ---------------------------------------------------------------------------
__global__ __launch_bounds__(256) void out_mfma(
        const u16* __restrict__ QF, const u16* __restrict__ KVth,
        const u16* __restrict__ KVtl, const float* __restrict__ Z,
        float* __restrict__ out) {
    int o = (blockIdx.x & 7) * 128 + (blockIdx.x >> 3);
    const int dt = o & 3, rt = o >> 2;
    const int row0 = rt * 128, b = row0 >> 13;
    const u16* Ag = QF + (size_t)row0 * 256;
    const u16* Bh_g = KVth + ((size_t)(b * 512 + dt * 128)) * 256;
    const u16* Bl_g = KVtl + ((size_t)(b * 512 + dt * 128)) * 256;
    __shared__ __align__(16) u16 A_[128 * 32], Bh_[128 * 32], Bl_[128 * 32];
    const int t = threadIdx.x, lane = t & 63;
    const int wid = t >> 6, wr = wid >> 1, wc = wid & 1;
    const int l15 = lane & 15, l4 = lane >> 4;
    const int koff = (l4 ^ ((l15 >> 1) & 3)) * 8;
    const u16* asrc[2];
    const u16* bhsrc[2];
    const u16* blsrc[2];
#pragma unroll
    for (int it = 0; it < 2; ++it) {
        const int row = it * 64 + wid * 16 + (lane >> 2);
        const int swz = ((lane & 3) ^ ((row >> 1) & 3)) * 8;
        asrc[it]  = Ag + (size_t)row * 256 + swz;
        bhsrc[it] = Bh_g + (size_t)row * 256 + swz;
        blsrc[it] = Bl_g + (size_t)row * 256 + swz;
    }
    f32x4 acc[4][4];
#pragma unroll
    for (int i = 0; i < 4; ++i)
#pragma unroll
        for (int j = 0; j < 4; ++j) acc[i][j] = (f32x4){0.f, 0.f, 0.f, 0.f};

    for (int kt = 0; kt < 8; ++kt) {
        __syncthreads();
#pragma unroll
        for (int it = 0; it < 2; ++it) {
            GLDS16(asrc[it], A_ + it * 2048 + wid * 512);
            GLDS16(bhsrc[it], Bh_ + it * 2048 + wid * 512);
            GLDS16(blsrc[it], Bl_ + it * 2048 + wid * 512);
            asrc[it] += 32; bhsrc[it] += 32; blsrc[it] += 32;
        }
        __syncthreads();
        bf16x8 a[4], bh[4], bl[4];
#pragma unroll
        for (int mf = 0; mf < 4; ++mf)
            a[mf] = *reinterpret_cast<const bf16x8*>(&A_[(wr * 64 + mf * 16 + l15) * 32 + koff]);
#pragma unroll
        for (int nf = 0; nf < 4; ++nf) {
            int r = (wc * 64 + nf * 16 + l15) * 32 + koff;
            bh[nf] = *reinterpret_cast<const bf16x8*>(&Bh_[r]);
            bl[nf] = *reinterpret_cast<const bf16x8*>(&Bl_[r]);
        }
#pragma unroll
        for (int mf = 0; mf < 4; ++mf)
#pragma unroll
            for (int nf = 0; nf < 4; ++nf) {
                acc[mf][nf] = __builtin_amdgcn_mfma_f32_16x16x32_bf16(a[mf], bh[nf], acc[mf][nf], 0, 0, 0);
                acc[mf][nf] = __builtin_amdgcn_mfma_f32_16x16x32_bf16(a[mf], bl[nf], acc[mf][nf], 0, 0, 0);
            }
    }
#pragma unroll
    for (int mf = 0; mf < 4; ++mf)
#pragma unroll
        for (int r = 0; r < 4; ++r) {
            const int row = row0 + wr * 64 + mf * 16 + l4 * 4 + r;
            const float z = Z[row];
#pragma unroll
            for (int nf = 0; nf < 4; ++nf)
                out[(size_t)row * 512 + dt * 128 + wc * 64 + nf * 16 + l15] = acc[mf][nf][r] * z;
        }
}

extern "C" void kernel_launch(void* const* d_in, const int* in_sizes, int n_in,
                              void* d_out, int out_size, void* d_ws, size_t ws_size,
                              hipStream_t stream) {
    const float* Q = (const float*)d_in[0];
    const float* K = (const float*)d_in[1];
    const float* V = (const float*)d_in[2];
    const float* P = (const float*)d_in[3];
    float* out = (float*)d_out;
    char* ws = (char*)d_ws;

    u16*   QF    = (u16*)(ws + 0);             // 16 MiB
    u16*   KfT   = (u16*)(ws + 16777216);      // 16 MiB (transposed, fused)
    u16*   Vt    = (u16*)(ws + 33554432);      // 32 MiB
    float* kvp   = (float*)(ws + 67108864);    // 32 MiB (16 chunks)
    u16*   KVth  = (u16*)(ws + 100663296);     // 1 MiB
    u16*   KVtl  = (u16*)(ws + 101711872);     // 1 MiB
    u16*   PH    = (u16*)(ws + 102760448);     // 256 KiB
    u16*   PL    = (u16*)(ws + 103022592);     // 256 KiB
    float* ksump = (float*)(ws + 103284736);   // 512 KiB
    float* vsump = (float*)(ws + 103809024);   // 1 MiB
    float* KsumT = (float*)(ws + 104857600);   // 4 KiB
    float* Vsum  = (float*)(ws + 104861696);   // 8 KiB
    float* Zbuf  = (float*)(ws + 104869888);   // 128 KiB
    u32*   bmax  = (u32*)(ws + 105000960);     // 16 B

    split_p<<<256, 256, 0, stream>>>(P, PH, PL, bmax);
    dash_all<<<1024, 256, 0, stream>>>(Q, K, PH, PL, QF, KfT, ksump, bmax);
    split_vt<<<4096, 256, 0, stream>>>(V, Vt, vsump);
    ksum_red<<<4, 256, 0, stream>>>(ksump, bmax, KsumT);
    vsum_red<<<8, 256, 0, stream>>>(vsump, Vsum);
    kv_mfma<<<512, 256, 0, stream>>>(KfT, Vt, kvp);
    kv_fix<<<128, 256, 0, stream>>>(kvp, bmax, Vsum, KVth, KVtl);
    z_kernel<<<8192, 256, 0, stream>>>(QF, KsumT, Zbuf);
    out_mfma<<<1024, 256, 0, stream>>>(QF, KVth, KVtl, Zbuf, out);
}